// Round 8
// baseline (702.898 us; speedup 1.0000x reference)
//
#include <hip/hip_runtime.h>
#include <hip/hip_bf16.h>

#define N_NODES 32768
#define N_EDGES 196608
#define N_GRAPHS 256
#define DEG 6
#define HID 128
#define RVD 16
#define EMB 112
#define VOCAB 128
#define TGT 256
#define DEPTH 5

#define LOG7 1.9459101090932196f
#define ILOG7 0.5138983423697507f

typedef __hip_bfloat16 bf16;
using frag_ab = __attribute__((ext_vector_type(8))) short;   // 8 bf16
using frag_cd = __attribute__((ext_vector_type(4))) float;   // 4 f32

static __device__ __forceinline__ float b2f(bf16 x) { return __bfloat162float(x); }
static __device__ __forceinline__ bf16  f2b(float x) { return __float2bfloat16(x); }

// ---------------- encoders ----------------
__global__ void encode_nodes(const int* __restrict__ af, const float* __restrict__ rx,
                             const float* __restrict__ emb, bf16* __restrict__ h) {
    int v = blockIdx.x, c = threadIdx.x;
    float val;
    if (c < EMB) {
        val = 0.f;
        #pragma unroll
        for (int i = 0; i < 9; ++i) {
            int f = af[v * 9 + i];
            val += emb[(i * VOCAB + f) * EMB + c];
        }
    } else {
        val = rx[v * RVD + (c - EMB)];
    }
    h[(size_t)v * HID + c] = f2b(val);
}

// ---------------- bond factorization ----------------
__global__ void bond_code_k(const int* __restrict__ bfeat, unsigned char* __restrict__ code) {
    int e = blockIdx.x * 256 + threadIdx.x;
    if (e < N_EDGES)
        code[e] = (unsigned char)(bfeat[e * 3] | (bfeat[e * 3 + 1] << 2) | (bfeat[e * 3 + 2] << 4));
}

__global__ void bond_sum_k(const float* __restrict__ bemb, float* __restrict__ bs) {
    int code = blockIdx.x, k = threadIdx.x;   // 64 blocks x 112
    int f0 = code & 3, f1 = (code >> 2) & 3, f2 = code >> 4;
    bs[code * EMB + k] = bemb[(0 * VOCAB + f0) * EMB + k]
                       + bemb[(1 * VOCAB + f1) * EMB + k]
                       + bemb[(2 * VOCAB + f2) * EMB + k];
}

// Tb[l][code][c] = bondsum[code] @ preW[l][256:368][c] + pre_b[l][c]   (bf16 table, bias folded)
__global__ void bond_T_k(const float* __restrict__ bs, const float* __restrict__ preW,
                         const float* __restrict__ preB, bf16* __restrict__ Tb) {
    int l = blockIdx.x >> 6, code = blockIdx.x & 63, c = threadIdx.x;
    const float* W = preW + (size_t)l * 384 * 128 + 256 * 128;
    float acc = preB[l * 128 + c];
    #pragma unroll 4
    for (int k = 0; k < EMB; ++k) acc += bs[code * EMB + k] * W[k * 128 + c];
    Tb[(size_t)(l * 64 + code) * 128 + c] = f2b(acc);
}

// ---------------- weight packing into MFMA B-fragment layout ----------------
// B frag elem linear index: ((ks*NT + nt)*64 + lane)*8 + j
// maps to B[k = ks*32 + (lane>>4)*8 + j][n = nt*16 + (lane&15)]

__global__ void pack_wb(const float* __restrict__ preW, bf16* __restrict__ out) {
    int idx = blockIdx.x * 256 + threadIdx.x;
    if (idx >= DEPTH * 32768) return;
    int j = idx & 7, L = (idx >> 3) & 63, nt = (idx >> 9) & 15, ks = (idx >> 13) & 3, l = idx >> 15;
    int k = ks * 32 + ((L >> 4) * 8) + j;
    int n = nt * 16 + (L & 15);
    const float* W = preW + (size_t)l * 384 * 128;
    float v = (n < 128) ? W[k * 128 + n] : W[(128 + k) * 128 + (n - 128)];
    out[idx] = f2b(v);
}

__global__ void pack_wc(const float* __restrict__ postW, bf16* __restrict__ out) {
    int idx = blockIdx.x * 256 + threadIdx.x;
    if (idx >= DEPTH * 81920) return;
    int j = idx & 7, L = (idx >> 3) & 63, nt = (idx >> 9) & 7;
    int t = idx >> 12;
    int ks = t % 20, l = t / 20;
    int k = ks * 32 + ((L >> 4) * 8) + j;
    int n = nt * 16 + (L & 15);
    const float* W = postW + (size_t)l * 1664 * 128;
    float v;
    if (k < 128) {
        v = W[k * 128 + n];
    } else {
        int jj = k - 128;
        v = W[(128 + jj) * 128 + n] + LOG7 * W[(640 + jj) * 128 + n] + ILOG7 * W[(1152 + jj) * 128 + n];
    }
    out[idx] = f2b(v);
}

// ---------------- layer-0 Z12 GEMM: z12 = h @ wb0 ----------------
__global__ __launch_bounds__(256) void gemm_z12(const bf16* __restrict__ A,
                                                const bf16* __restrict__ Bp,
                                                bf16* __restrict__ C) {
    int lane = threadIdx.x & 63;
    int wave = threadIdx.x >> 6;
    int m = lane & 15, quad = lane >> 4;
    int row0 = blockIdx.x * 64 + wave * 16;

    frag_cd acc[16];
    #pragma unroll
    for (int nt = 0; nt < 16; ++nt)
        #pragma unroll
        for (int i = 0; i < 4; ++i) acc[nt][i] = 0.f;

    const frag_ab* Bf = (const frag_ab*)Bp;
    const bf16* arow = A + (size_t)(row0 + m) * 128;
    #pragma unroll
    for (int ks = 0; ks < 4; ++ks) {
        frag_ab a = *(const frag_ab*)(arow + ks * 32 + quad * 8);
        #pragma unroll
        for (int nt = 0; nt < 16; ++nt) {
            frag_ab b = Bf[(ks * 16 + nt) * 64 + lane];
            acc[nt] = __builtin_amdgcn_mfma_f32_16x16x32_bf16(a, b, acc[nt], 0, 0, 0);
        }
    }
    #pragma unroll
    for (int nt = 0; nt < 16; ++nt) {
        int col = nt * 16 + m;
        #pragma unroll
        for (int r = 0; r < 4; ++r) {
            int row = row0 + quad * 4 + r;
            C[(size_t)row * 256 + col] = f2b(acc[nt][r]);
        }
    }
}

// ---------------- merged layer kernel ----------------
// 1024 blocks x 512 threads, 32 nodes/block.
// A: aggregation (gathers from zin) -> aggL (LDS)
// B: posttrans GEMM: A-frags from h (global, k<128) + aggL (k>=128)
// C: epilogue: h += ... in place (bf16), newh to LDS (overlays rnd region)
// D: next-layer z12 = newh @ Bn -> zout  (ping-pong vs zin)
__global__ __launch_bounds__(512) void layer_merged(const bf16* __restrict__ zin,
                                                    bf16* __restrict__ h,
                                                    const int* __restrict__ src,
                                                    const unsigned char* __restrict__ code,
                                                    const float* __restrict__ rand_edge,
                                                    const bf16* __restrict__ Tb,
                                                    const float* __restrict__ Wr,
                                                    const bf16* __restrict__ Bp,
                                                    const float* __restrict__ bias,
                                                    const bf16* __restrict__ Bn,
                                                    bf16* __restrict__ zout) {
    __shared__ __align__(16) bf16 aggL[32 * 520];   // 33.3 KB ; stride 520: 16B-aligned rows, 2-way banks
    __shared__ __align__(16) float rndL[3072];      // 12 KB   ; dead after phase A
    bf16* newh = (bf16*)rndL;                       // 32*136*2 = 8.7 KB overlay

    int tid = threadIdx.x;
    int row0 = blockIdx.x * 32;

    // stage rand_edge: 32 nodes * 6 edges * 16 f32
    {
        const float4* rp = (const float4*)(rand_edge + (size_t)row0 * 96);
        float4* dp = (float4*)rndL;
        for (int k = tid; k < 768; k += 512) dp[k] = rp[k];
    }
    __syncthreads();

    // ---- phase A: aggregation (2-node pairs, R6-style modest VGPR) ----
    {
        int c = tid & 127, cg = tid >> 7;
        float wr[16];
        #pragma unroll
        for (int r = 0; r < 16; ++r) wr[r] = Wr[r * 128 + c];

        for (int i0 = 0; i0 < 8; i0 += 2) {
            int svs[2][6], cds[2][6];
            #pragma unroll
            for (int p = 0; p < 2; ++p) {
                int v = row0 + cg * 8 + i0 + p;
                const int2* sp = (const int2*)(src + v * 6);
                int2 s01 = sp[0], s23 = sp[1], s45 = sp[2];
                const unsigned short* cp = (const unsigned short*)(code + v * 6);
                unsigned short c01 = cp[0], c23 = cp[1], c45 = cp[2];
                svs[p][0] = s01.x; svs[p][1] = s01.y; svs[p][2] = s23.x;
                svs[p][3] = s23.y; svs[p][4] = s45.x; svs[p][5] = s45.y;
                cds[p][0] = c01 & 255; cds[p][1] = c01 >> 8; cds[p][2] = c23 & 255;
                cds[p][3] = c23 >> 8;  cds[p][4] = c45 & 255; cds[p][5] = c45 >> 8;
            }
            float z1[2][6], tv[2][6], z2[2];
            #pragma unroll
            for (int p = 0; p < 2; ++p) {
                int v = row0 + cg * 8 + i0 + p;
                z2[p] = b2f(zin[(size_t)v * 256 + 128 + c]);
                #pragma unroll
                for (int j = 0; j < 6; ++j) z1[p][j] = b2f(zin[(size_t)svs[p][j] * 256 + c]);
                #pragma unroll
                for (int j = 0; j < 6; ++j) tv[p][j] = b2f(Tb[cds[p][j] * 128 + c]);
            }
            #pragma unroll
            for (int p = 0; p < 2; ++p) {
                int lr = cg * 8 + i0 + p;
                float s = 0.f, ss = 0.f, mx = -1e30f, mn = 1e30f;
                #pragma unroll
                for (int j = 0; j < 6; ++j) {
                    float val = z1[p][j] + z2[p] + tv[p][j];
                    const float4* rp4 = (const float4*)(rndL + (lr * 6 + j) * 16);
                    float4 r0 = rp4[0], r1 = rp4[1], r2 = rp4[2], r3 = rp4[3];
                    val += r0.x * wr[0] + r0.y * wr[1] + r0.z * wr[2] + r0.w * wr[3]
                         + r1.x * wr[4] + r1.y * wr[5] + r1.z * wr[6] + r1.w * wr[7]
                         + r2.x * wr[8] + r2.y * wr[9] + r2.z * wr[10] + r2.w * wr[11]
                         + r3.x * wr[12] + r3.y * wr[13] + r3.z * wr[14] + r3.w * wr[15];
                    val = fmaxf(val, 0.f);
                    s += val; ss += val * val; mx = fmaxf(mx, val); mn = fminf(mn, val);
                }
                float mean = s * (1.f / 6.f);
                float msq = ss * (1.f / 6.f);
                float sd = sqrtf(fmaxf(msq - mean * mean, 0.f) + 1e-5f);
                aggL[lr * 520 + c]       = f2b(mean);
                aggL[lr * 520 + 128 + c] = f2b(mx);
                aggL[lr * 520 + 256 + c] = f2b(mn);
                aggL[lr * 520 + 384 + c] = f2b(sd);
            }
        }
    }
    __syncthreads();   // aggL ready; rndL dead

    // ---- phase B: posttrans GEMM ----
    int lane = tid & 63;
    int wave = tid >> 6;
    int rt = wave & 1;        // row-tile 0..1
    int nh = wave >> 1;       // col-quarter 0..3
    int m = lane & 15, quad = lane >> 4;

    frag_cd acc[2];
    #pragma unroll
    for (int nt = 0; nt < 2; ++nt)
        #pragma unroll
        for (int i = 0; i < 4; ++i) acc[nt][i] = 0.f;

    const frag_ab* Bf = (const frag_ab*)Bp;
    const bf16* arow = h + (size_t)(row0 + rt * 16 + m) * 128;
    #pragma unroll
    for (int ks = 0; ks < 4; ++ks) {
        frag_ab a = *(const frag_ab*)(arow + ks * 32 + quad * 8);
        #pragma unroll
        for (int nt = 0; nt < 2; ++nt) {
            frag_ab b = Bf[(ks * 8 + nh * 2 + nt) * 64 + lane];
            acc[nt] = __builtin_amdgcn_mfma_f32_16x16x32_bf16(a, b, acc[nt], 0, 0, 0);
        }
    }
    const bf16* lrow = &aggL[(rt * 16 + m) * 520];
    #pragma unroll
    for (int ks = 0; ks < 16; ++ks) {
        frag_ab a = *(const frag_ab*)(lrow + ks * 32 + quad * 8);
        #pragma unroll
        for (int nt = 0; nt < 2; ++nt) {
            frag_ab b = Bf[((4 + ks) * 8 + nh * 2 + nt) * 64 + lane];
            acc[nt] = __builtin_amdgcn_mfma_f32_16x16x32_bf16(a, b, acc[nt], 0, 0, 0);
        }
    }

    __syncthreads();   // all h reads + aggL reads done before in-place write / newh overlay

    // ---- phase C: epilogue ----
    #pragma unroll
    for (int nt = 0; nt < 2; ++nt) {
        int col = nh * 32 + nt * 16 + m;
        float bs_ = bias[col];
        #pragma unroll
        for (int r = 0; r < 4; ++r) {
            int lr = rt * 16 + quad * 4 + r;
            int row = row0 + lr;
            float nv = acc[nt][r] + bs_ + b2f(h[(size_t)row * HID + col]);
            bf16 bv = f2b(nv);
            h[(size_t)row * HID + col] = bv;
            newh[lr * 136 + col] = bv;
        }
    }

    // ---- phase D: next-layer z12 ----
    if (Bn) {
        __syncthreads();
        const frag_ab* Bf2 = (const frag_ab*)Bn;
        frag_cd a2[4];
        #pragma unroll
        for (int nt = 0; nt < 4; ++nt)
            #pragma unroll
            for (int i = 0; i < 4; ++i) a2[nt][i] = 0.f;
        #pragma unroll
        for (int ks = 0; ks < 4; ++ks) {
            frag_ab a = *(const frag_ab*)&newh[(rt * 16 + m) * 136 + ks * 32 + quad * 8];
            #pragma unroll
            for (int nt = 0; nt < 4; ++nt) {
                frag_ab b = Bf2[(ks * 16 + nh * 4 + nt) * 64 + lane];
                a2[nt] = __builtin_amdgcn_mfma_f32_16x16x32_bf16(a, b, a2[nt], 0, 0, 0);
            }
        }
        #pragma unroll
        for (int nt = 0; nt < 4; ++nt) {
            int col = nh * 64 + nt * 16 + m;
            #pragma unroll
            for (int r = 0; r < 4; ++r) {
                int row = row0 + rt * 16 + quad * 4 + r;
                zout[(size_t)row * 256 + col] = f2b(a2[nt][r]);
            }
        }
    }
}

// ---------------- readout ----------------
__global__ __launch_bounds__(128) void readout(const bf16* __restrict__ h, const float* __restrict__ W1,
                                               const float* __restrict__ b1, const float* __restrict__ W2,
                                               const float* __restrict__ b2, float* __restrict__ out) {
    __shared__ float r[384];
    __shared__ float y1[128];
    int g = blockIdx.x, c = threadIdx.x;
    float s = 0.f, mx = -1e30f;
    for (int v = 0; v < 128; ++v) {
        float hv = b2f(h[((size_t)g * 128 + v) * HID + c]);
        s += hv; mx = fmaxf(mx, hv);
    }
    r[c] = s * (1.f / 128.f);
    r[128 + c] = s;
    r[256 + c] = mx;
    __syncthreads();
    float a1 = b1[c];
    for (int k = 0; k < 384; ++k) a1 += r[k] * W1[k * 128 + c];
    y1[c] = fmaxf(a1, 0.f);
    __syncthreads();
    #pragma unroll
    for (int o = 0; o < 2; ++o) {
        int t = c + o * 128;
        float a2 = b2[t];
        for (int k = 0; k < 128; ++k) a2 += y1[k] * W2[k * 256 + t];
        out[(size_t)g * 256 + t] = a2;
    }
}

// ---------------- launch ----------------
extern "C" void kernel_launch(void* const* d_in, const int* in_sizes, int n_in,
                              void* d_out, int out_size, void* d_ws, size_t ws_size,
                              hipStream_t stream) {
    const int*   atom_feats = (const int*)d_in[0];
    const int*   bond_feats = (const int*)d_in[1];
    const int*   src        = (const int*)d_in[2];
    const float* rand_x     = (const float*)d_in[6];
    const float* rand_edge  = (const float*)d_in[7];
    const float* atom_emb   = (const float*)d_in[8];
    const float* bond_emb   = (const float*)d_in[9];
    const float* pre_W      = (const float*)d_in[10];
    const float* pre_b      = (const float*)d_in[11];
    const float* post_W     = (const float*)d_in[12];
    const float* post_b     = (const float*)d_in[13];
    const float* ro_W1      = (const float*)d_in[14];
    const float* ro_b1      = (const float*)d_in[15];
    const float* ro_W2      = (const float*)d_in[16];
    const float* ro_b2      = (const float*)d_in[17];

    char* p = (char*)d_ws;
    auto alloc = [&](size_t bytes) {
        char* r = p;
        p += (bytes + 255) & ~(size_t)255;
        return r;
    };
    bf16*  h    = (bf16*) alloc((size_t)N_NODES * HID * 2);      // 8 MB (bf16 state)
    bf16*  z12a = (bf16*) alloc((size_t)N_NODES * 256 * 2);      // 16 MB
    bf16*  z12b = (bf16*) alloc((size_t)N_NODES * 256 * 2);      // 16 MB
    bf16*  wb   = (bf16*) alloc((size_t)DEPTH * 32768 * 2);
    bf16*  wc   = (bf16*) alloc((size_t)DEPTH * 81920 * 2);
    bf16*  Tb   = (bf16*) alloc((size_t)DEPTH * 64 * 128 * 2);   // 80 KB
    float* bs   = (float*)alloc((size_t)64 * EMB * 4);           // 28 KB
    unsigned char* code = (unsigned char*)alloc(N_EDGES);        // 192 KB

    pack_wb<<<(DEPTH * 32768 + 255) / 256, 256, 0, stream>>>(pre_W, wb);
    pack_wc<<<(DEPTH * 81920 + 255) / 256, 256, 0, stream>>>(post_W, wc);
    bond_code_k<<<(N_EDGES + 255) / 256, 256, 0, stream>>>(bond_feats, code);
    bond_sum_k<<<64, EMB, 0, stream>>>(bond_emb, bs);
    bond_T_k<<<DEPTH * 64, 128, 0, stream>>>(bs, pre_W, pre_b, Tb);

    encode_nodes<<<N_NODES, 128, 0, stream>>>(atom_feats, rand_x, atom_emb, h);

    // layer-0 Z12
    gemm_z12<<<N_NODES / 64, 256, 0, stream>>>(h, wb, z12a);

    for (int l = 0; l < DEPTH; ++l) {
        bf16* zin  = (l & 1) ? z12b : z12a;
        bf16* zout = (l & 1) ? z12a : z12b;
        const bf16* wbn = (l + 1 < DEPTH) ? (wb + (size_t)(l + 1) * 32768) : nullptr;
        layer_merged<<<N_NODES / 32, 512, 0, stream>>>(
            zin, h, src, code, rand_edge,
            Tb + (size_t)l * 8192,
            pre_W + (size_t)l * 49152 + 368 * 128,
            wc + (size_t)l * 81920, post_b + l * HID,
            wbn, zout);
    }

    readout<<<N_GRAPHS, 128, 0, stream>>>(h, ro_W1, ro_b1, ro_W2, ro_b2, (float*)d_out);
}

// Round 9
// 413.051 us; speedup vs baseline: 1.7017x; 1.7017x over previous
//
#include <hip/hip_runtime.h>
#include <hip/hip_bf16.h>

#define N_NODES 32768
#define N_EDGES 196608
#define N_GRAPHS 256
#define DEG 6
#define HID 128
#define RVD 16
#define EMB 112
#define VOCAB 128
#define TGT 256
#define DEPTH 5

#define LOG7 1.9459101090932196f
#define ILOG7 0.5138983423697507f

typedef __hip_bfloat16 bf16;
using frag_ab = __attribute__((ext_vector_type(8))) short;   // 8 bf16
using frag_cd = __attribute__((ext_vector_type(4))) float;   // 4 f32

static __device__ __forceinline__ float b2f(bf16 x) { return __bfloat162float(x); }
static __device__ __forceinline__ bf16  f2b(float x) { return __float2bfloat16(x); }

// ---------------- encoders ----------------
__global__ void encode_nodes(const int* __restrict__ af, const float* __restrict__ rx,
                             const float* __restrict__ emb, bf16* __restrict__ h) {
    int v = blockIdx.x, c = threadIdx.x;
    float val;
    if (c < EMB) {
        val = 0.f;
        #pragma unroll
        for (int i = 0; i < 9; ++i) {
            int f = af[v * 9 + i];
            val += emb[(i * VOCAB + f) * EMB + c];
        }
    } else {
        val = rx[v * RVD + (c - EMB)];
    }
    h[(size_t)v * HID + c] = f2b(val);
}

// ---------------- bond factorization ----------------
__global__ void bond_code_k(const int* __restrict__ bfeat, unsigned char* __restrict__ code) {
    int e = blockIdx.x * 256 + threadIdx.x;
    if (e < N_EDGES)
        code[e] = (unsigned char)(bfeat[e * 3] | (bfeat[e * 3 + 1] << 2) | (bfeat[e * 3 + 2] << 4));
}

__global__ void bond_sum_k(const float* __restrict__ bemb, float* __restrict__ bs) {
    int code = blockIdx.x, k = threadIdx.x;   // 64 blocks x 112
    int f0 = code & 3, f1 = (code >> 2) & 3, f2 = code >> 4;
    bs[code * EMB + k] = bemb[(0 * VOCAB + f0) * EMB + k]
                       + bemb[(1 * VOCAB + f1) * EMB + k]
                       + bemb[(2 * VOCAB + f2) * EMB + k];
}

// Tb[l][code][c] = bondsum[code] @ preW[l][256:368][c] + pre_b[l][c]   (bf16 table, bias folded)
__global__ void bond_T_k(const float* __restrict__ bs, const float* __restrict__ preW,
                         const float* __restrict__ preB, bf16* __restrict__ Tb) {
    int l = blockIdx.x >> 6, code = blockIdx.x & 63, c = threadIdx.x;
    const float* W = preW + (size_t)l * 384 * 128 + 256 * 128;
    float acc = preB[l * 128 + c];
    #pragma unroll 4
    for (int k = 0; k < EMB; ++k) acc += bs[code * EMB + k] * W[k * 128 + c];
    Tb[(size_t)(l * 64 + code) * 128 + c] = f2b(acc);
}

// ---------------- weight packing into MFMA B-fragment layout ----------------
// B frag elem linear index: ((ks*NT + nt)*64 + lane)*8 + j
// maps to B[k = ks*32 + (lane>>4)*8 + j][n = nt*16 + (lane&15)]

__global__ void pack_wb(const float* __restrict__ preW, bf16* __restrict__ out) {
    int idx = blockIdx.x * 256 + threadIdx.x;
    if (idx >= DEPTH * 32768) return;
    int j = idx & 7, L = (idx >> 3) & 63, nt = (idx >> 9) & 15, ks = (idx >> 13) & 3, l = idx >> 15;
    int k = ks * 32 + ((L >> 4) * 8) + j;
    int n = nt * 16 + (L & 15);
    const float* W = preW + (size_t)l * 384 * 128;
    float v = (n < 128) ? W[k * 128 + n] : W[(128 + k) * 128 + (n - 128)];
    out[idx] = f2b(v);
}

__global__ void pack_wc(const float* __restrict__ postW, bf16* __restrict__ out) {
    int idx = blockIdx.x * 256 + threadIdx.x;
    if (idx >= DEPTH * 81920) return;
    int j = idx & 7, L = (idx >> 3) & 63, nt = (idx >> 9) & 7;
    int t = idx >> 12;
    int ks = t % 20, l = t / 20;
    int k = ks * 32 + ((L >> 4) * 8) + j;
    int n = nt * 16 + (L & 15);
    const float* W = postW + (size_t)l * 1664 * 128;
    float v;
    if (k < 128) {
        v = W[k * 128 + n];
    } else {
        int jj = k - 128;
        v = W[(128 + jj) * 128 + n] + LOG7 * W[(640 + jj) * 128 + n] + ILOG7 * W[(1152 + jj) * 128 + n];
    }
    out[idx] = f2b(v);
}

// ---------------- layer-0 Z12 GEMM: z12 = h @ wb0 ----------------
__global__ __launch_bounds__(256) void gemm_z12(const bf16* __restrict__ A,
                                                const bf16* __restrict__ Bp,
                                                bf16* __restrict__ C) {
    int lane = threadIdx.x & 63;
    int wave = threadIdx.x >> 6;
    int m = lane & 15, quad = lane >> 4;
    int row0 = blockIdx.x * 64 + wave * 16;

    frag_cd acc[16];
    #pragma unroll
    for (int nt = 0; nt < 16; ++nt)
        #pragma unroll
        for (int i = 0; i < 4; ++i) acc[nt][i] = 0.f;

    const frag_ab* Bf = (const frag_ab*)Bp;
    const bf16* arow = A + (size_t)(row0 + m) * 128;
    #pragma unroll
    for (int ks = 0; ks < 4; ++ks) {
        frag_ab a = *(const frag_ab*)(arow + ks * 32 + quad * 8);
        #pragma unroll
        for (int nt = 0; nt < 16; ++nt) {
            frag_ab b = Bf[(ks * 16 + nt) * 64 + lane];
            acc[nt] = __builtin_amdgcn_mfma_f32_16x16x32_bf16(a, b, acc[nt], 0, 0, 0);
        }
    }
    #pragma unroll
    for (int nt = 0; nt < 16; ++nt) {
        int col = nt * 16 + m;
        #pragma unroll
        for (int r = 0; r < 4; ++r) {
            int row = row0 + quad * 4 + r;
            C[(size_t)row * 256 + col] = f2b(acc[nt][r]);
        }
    }
}

// ---------------- fused posttrans + residual + next-layer Z12 ----------------
// 64-row tile, 512 threads / 8 waves: wave = (rt 0..3, nh 0..1). grid = N/64 = 512.
__global__ __launch_bounds__(512) void layer_k(bf16* __restrict__ h,       // bf16 state, in-place
                                               const bf16* __restrict__ aggc,
                                               const bf16* __restrict__ Bp,
                                               const float* __restrict__ bias,
                                               const bf16* __restrict__ Bn,
                                               bf16* __restrict__ z12) {
    __shared__ __align__(16) bf16 newh[64 * 136];   // pad 136: b128-aligned rows
    int lane = threadIdx.x & 63;
    int wave = threadIdx.x >> 6;
    int rt = wave & 3;        // row-tile
    int nh = wave >> 2;       // col-half
    int m = lane & 15, quad = lane >> 4;
    int row0 = blockIdx.x * 64;
    int rowA = row0 + rt * 16 + m;

    frag_cd acc[4];
    #pragma unroll
    for (int nt = 0; nt < 4; ++nt)
        #pragma unroll
        for (int i = 0; i < 4; ++i) acc[nt][i] = 0.f;

    const frag_ab* Bf = (const frag_ab*)Bp;
    const bf16* arow = h + (size_t)rowA * 128;
    #pragma unroll
    for (int ks = 0; ks < 4; ++ks) {
        frag_ab a = *(const frag_ab*)(arow + ks * 32 + quad * 8);
        #pragma unroll
        for (int nt = 0; nt < 4; ++nt) {
            frag_ab b = Bf[(ks * 8 + nh * 4 + nt) * 64 + lane];
            acc[nt] = __builtin_amdgcn_mfma_f32_16x16x32_bf16(a, b, acc[nt], 0, 0, 0);
        }
    }
    const bf16* grow = aggc + (size_t)rowA * 512;
    #pragma unroll
    for (int ks = 0; ks < 16; ++ks) {
        frag_ab a = *(const frag_ab*)(grow + ks * 32 + quad * 8);
        #pragma unroll
        for (int nt = 0; nt < 4; ++nt) {
            frag_ab b = Bf[((4 + ks) * 8 + nh * 4 + nt) * 64 + lane];
            acc[nt] = __builtin_amdgcn_mfma_f32_16x16x32_bf16(a, b, acc[nt], 0, 0, 0);
        }
    }

    __syncthreads();   // all waves done reading h rows before any in-place write

    #pragma unroll
    for (int nt = 0; nt < 4; ++nt) {
        int col = nh * 64 + nt * 16 + m;
        float bs_ = bias[col];
        #pragma unroll
        for (int r = 0; r < 4; ++r) {
            int lr = rt * 16 + quad * 4 + r;
            int row = row0 + lr;
            float nv = acc[nt][r] + bs_ + b2f(h[(size_t)row * HID + col]);
            bf16 bv = f2b(nv);
            h[(size_t)row * HID + col] = bv;
            newh[lr * 136 + col] = bv;
        }
    }

    if (Bn) {
        __syncthreads();
        const frag_ab* Bf2 = (const frag_ab*)Bn;
        frag_cd a2[8];
        #pragma unroll
        for (int nt = 0; nt < 8; ++nt)
            #pragma unroll
            for (int i = 0; i < 4; ++i) a2[nt][i] = 0.f;
        #pragma unroll
        for (int ks = 0; ks < 4; ++ks) {
            frag_ab a = *(const frag_ab*)&newh[(rt * 16 + m) * 136 + ks * 32 + quad * 8];
            #pragma unroll
            for (int nt = 0; nt < 8; ++nt) {
                frag_ab b = Bf2[(ks * 16 + nh * 8 + nt) * 64 + lane];
                a2[nt] = __builtin_amdgcn_mfma_f32_16x16x32_bf16(a, b, a2[nt], 0, 0, 0);
            }
        }
        #pragma unroll
        for (int nt = 0; nt < 8; ++nt) {
            int col = nh * 128 + nt * 16 + m;
            #pragma unroll
            for (int r = 0; r < 4; ++r) {
                int row = row0 + rt * 16 + quad * 4 + r;
                z12[(size_t)row * 256 + col] = f2b(a2[nt][r]);
            }
        }
    }
}

// ---------------- fused edge-transform + aggregation (R6 hybrid form) ----------------
// LDS: rnd only (3 KB). Tb read direct (coalesced 128B wave-load, L1-resident 16 KB table).
__global__ __launch_bounds__(256) void fused_agg(const bf16* __restrict__ Z12,
                                                 const int* __restrict__ src,
                                                 const unsigned char* __restrict__ code,
                                                 const float* __restrict__ rand_edge,
                                                 const bf16* __restrict__ Tb,
                                                 const float* __restrict__ Wr,
                                                 bf16* __restrict__ aggc) {
    __shared__ float rnd[768];    // 48 edges * 16 f32 = 3 KB
    int tid = threadIdx.x;
    int bv = blockIdx.x * 8;

    if (tid < 192) ((float4*)rnd)[tid] = ((const float4*)rand_edge)[(size_t)blockIdx.x * 192 + tid];
    __syncthreads();

    int c = tid & 127, half = tid >> 7;
    float wr[16];
    #pragma unroll
    for (int r = 0; r < 16; ++r) wr[r] = Wr[r * 128 + c];

    #pragma unroll
    for (int i = 0; i < 4; ++i) {
        int nb = half * 4 + i;
        int v = bv + nb;
        float z2 = b2f(Z12[(size_t)v * 256 + 128 + c]);
        const int2* sp = (const int2*)(src + v * 6);
        int2 s01 = sp[0], s23 = sp[1], s45 = sp[2];
        const unsigned short* cp = (const unsigned short*)(code + v * 6);
        unsigned short c01 = cp[0], c23 = cp[1], c45 = cp[2];
        int svs[6] = { s01.x, s01.y, s23.x, s23.y, s45.x, s45.y };
        int cds[6] = { c01 & 255, c01 >> 8, c23 & 255, c23 >> 8, c45 & 255, c45 >> 8 };
        float z1[6], tv[6];
        #pragma unroll
        for (int j = 0; j < 6; ++j) z1[j] = b2f(Z12[(size_t)svs[j] * 256 + c]);
        #pragma unroll
        for (int j = 0; j < 6; ++j) tv[j] = b2f(Tb[cds[j] * 128 + c]);
        float s = 0.f, ss = 0.f, mx = -1e30f, mn = 1e30f;
        #pragma unroll
        for (int j = 0; j < 6; ++j) {
            float val = z1[j] + z2 + tv[j];
            const float4* rp = (const float4*)(rnd + (nb * 6 + j) * 16);
            float4 r0 = rp[0], r1 = rp[1], r2 = rp[2], r3 = rp[3];
            val += r0.x * wr[0] + r0.y * wr[1] + r0.z * wr[2] + r0.w * wr[3]
                 + r1.x * wr[4] + r1.y * wr[5] + r1.z * wr[6] + r1.w * wr[7]
                 + r2.x * wr[8] + r2.y * wr[9] + r2.z * wr[10] + r2.w * wr[11]
                 + r3.x * wr[12] + r3.y * wr[13] + r3.z * wr[14] + r3.w * wr[15];
            val = fmaxf(val, 0.f);
            s += val; ss += val * val; mx = fmaxf(mx, val); mn = fminf(mn, val);
        }
        float mean = s * (1.f / 6.f);
        float msq = ss * (1.f / 6.f);
        float sd = sqrtf(fmaxf(msq - mean * mean, 0.f) + 1e-5f);
        size_t base = (size_t)v * 512;
        aggc[base + c]       = f2b(mean);
        aggc[base + 128 + c] = f2b(mx);
        aggc[base + 256 + c] = f2b(mn);
        aggc[base + 384 + c] = f2b(sd);
    }
}

// ---------------- readout ----------------
__global__ __launch_bounds__(128) void readout(const bf16* __restrict__ h, const float* __restrict__ W1,
                                               const float* __restrict__ b1, const float* __restrict__ W2,
                                               const float* __restrict__ b2, float* __restrict__ out) {
    __shared__ float r[384];
    __shared__ float y1[128];
    int g = blockIdx.x, c = threadIdx.x;
    float s = 0.f, mx = -1e30f;
    for (int v = 0; v < 128; ++v) {
        float hv = b2f(h[((size_t)g * 128 + v) * HID + c]);
        s += hv; mx = fmaxf(mx, hv);
    }
    r[c] = s * (1.f / 128.f);
    r[128 + c] = s;
    r[256 + c] = mx;
    __syncthreads();
    float a1 = b1[c];
    for (int k = 0; k < 384; ++k) a1 += r[k] * W1[k * 128 + c];
    y1[c] = fmaxf(a1, 0.f);
    __syncthreads();
    #pragma unroll
    for (int o = 0; o < 2; ++o) {
        int t = c + o * 128;
        float a2 = b2[t];
        for (int k = 0; k < 128; ++k) a2 += y1[k] * W2[k * 256 + t];
        out[(size_t)g * 256 + t] = a2;
    }
}

// ---------------- launch ----------------
extern "C" void kernel_launch(void* const* d_in, const int* in_sizes, int n_in,
                              void* d_out, int out_size, void* d_ws, size_t ws_size,
                              hipStream_t stream) {
    const int*   atom_feats = (const int*)d_in[0];
    const int*   bond_feats = (const int*)d_in[1];
    const int*   src        = (const int*)d_in[2];
    const float* rand_x     = (const float*)d_in[6];
    const float* rand_edge  = (const float*)d_in[7];
    const float* atom_emb   = (const float*)d_in[8];
    const float* bond_emb   = (const float*)d_in[9];
    const float* pre_W      = (const float*)d_in[10];
    const float* pre_b      = (const float*)d_in[11];
    const float* post_W     = (const float*)d_in[12];
    const float* post_b     = (const float*)d_in[13];
    const float* ro_W1      = (const float*)d_in[14];
    const float* ro_b1      = (const float*)d_in[15];
    const float* ro_W2      = (const float*)d_in[16];
    const float* ro_b2      = (const float*)d_in[17];

    char* p = (char*)d_ws;
    auto alloc = [&](size_t bytes) {
        char* r = p;
        p += (bytes + 255) & ~(size_t)255;
        return r;
    };
    bf16*  h    = (bf16*) alloc((size_t)N_NODES * HID * 2);      // 8 MB (bf16 state)
    bf16*  z12  = (bf16*) alloc((size_t)N_NODES * 256 * 2);      // 16 MB
    bf16*  aggc = (bf16*) alloc((size_t)N_NODES * 512 * 2);      // 32 MB
    bf16*  wb   = (bf16*) alloc((size_t)DEPTH * 32768 * 2);
    bf16*  wc   = (bf16*) alloc((size_t)DEPTH * 81920 * 2);
    bf16*  Tb   = (bf16*) alloc((size_t)DEPTH * 64 * 128 * 2);   // 80 KB
    float* bs   = (float*)alloc((size_t)64 * EMB * 4);           // 28 KB
    unsigned char* code = (unsigned char*)alloc(N_EDGES);        // 192 KB

    pack_wb<<<(DEPTH * 32768 + 255) / 256, 256, 0, stream>>>(pre_W, wb);
    pack_wc<<<(DEPTH * 81920 + 255) / 256, 256, 0, stream>>>(post_W, wc);
    bond_code_k<<<(N_EDGES + 255) / 256, 256, 0, stream>>>(bond_feats, code);
    bond_sum_k<<<64, EMB, 0, stream>>>(bond_emb, bs);
    bond_T_k<<<DEPTH * 64, 128, 0, stream>>>(bs, pre_W, pre_b, Tb);

    encode_nodes<<<N_NODES, 128, 0, stream>>>(atom_feats, rand_x, atom_emb, h);

    // layer-0 Z12
    gemm_z12<<<N_NODES / 64, 256, 0, stream>>>(h, wb, z12);

    for (int l = 0; l < DEPTH; ++l) {
        fused_agg<<<N_NODES / 8, 256, 0, stream>>>(
            z12, src, code, rand_edge,
            Tb + (size_t)l * 8192,
            pre_W + (size_t)l * 49152 + 368 * 128, aggc);
        const bf16* wbn = (l + 1 < DEPTH) ? (wb + (size_t)(l + 1) * 32768) : nullptr;
        layer_k<<<N_NODES / 64, 512, 0, stream>>>(
            h, aggc, wc + (size_t)l * 81920, post_b + l * HID, wbn, z12);
    }

    readout<<<N_GRAPHS, 128, 0, stream>>>(h, ro_W1, ro_b1, ro_W2, ro_b2, (float*)d_out);
}

// Round 10
// 407.280 us; speedup vs baseline: 1.7258x; 1.0142x over previous
//
#include <hip/hip_runtime.h>
#include <hip/hip_bf16.h>

#define N_NODES 32768
#define N_EDGES 196608
#define N_GRAPHS 256
#define DEG 6
#define HID 128
#define RVD 16
#define EMB 112
#define VOCAB 128
#define TGT 256
#define DEPTH 5

#define LOG7 1.9459101090932196f
#define ILOG7 0.5138983423697507f

typedef __hip_bfloat16 bf16;
using frag_ab = __attribute__((ext_vector_type(8))) short;   // 8 bf16
using frag_cd = __attribute__((ext_vector_type(4))) float;   // 4 f32

static __device__ __forceinline__ float b2f(bf16 x) { return __bfloat162float(x); }
static __device__ __forceinline__ bf16  f2b(float x) { return __float2bfloat16(x); }
static __device__ __forceinline__ short f2s(float x) {
    bf16 b = __float2bfloat16(x);
    return *reinterpret_cast<short*>(&b);
}

// ---------------- encoders ----------------
__global__ void encode_nodes(const int* __restrict__ af, const float* __restrict__ rx,
                             const float* __restrict__ emb, bf16* __restrict__ h) {
    int v = blockIdx.x, c = threadIdx.x;
    float val;
    if (c < EMB) {
        val = 0.f;
        #pragma unroll
        for (int i = 0; i < 9; ++i) {
            int f = af[v * 9 + i];
            val += emb[(i * VOCAB + f) * EMB + c];
        }
    } else {
        val = rx[v * RVD + (c - EMB)];
    }
    h[(size_t)v * HID + c] = f2b(val);
}

// ---------------- bond factorization ----------------
__global__ void bond_code_k(const int* __restrict__ bfeat, unsigned char* __restrict__ code) {
    int e = blockIdx.x * 256 + threadIdx.x;
    if (e < N_EDGES)
        code[e] = (unsigned char)(bfeat[e * 3] | (bfeat[e * 3 + 1] << 2) | (bfeat[e * 3 + 2] << 4));
}

__global__ void bond_sum_k(const float* __restrict__ bemb, float* __restrict__ bs) {
    int code = blockIdx.x, k = threadIdx.x;   // 64 blocks x 112
    int f0 = code & 3, f1 = (code >> 2) & 3, f2 = code >> 4;
    bs[code * EMB + k] = bemb[(0 * VOCAB + f0) * EMB + k]
                       + bemb[(1 * VOCAB + f1) * EMB + k]
                       + bemb[(2 * VOCAB + f2) * EMB + k];
}

// Tb[l][code][c] = bondsum[code] @ preW[l][256:368][c] + pre_b[l][c]   (bf16 table, bias folded)
__global__ void bond_T_k(const float* __restrict__ bs, const float* __restrict__ preW,
                         const float* __restrict__ preB, bf16* __restrict__ Tb) {
    int l = blockIdx.x >> 6, code = blockIdx.x & 63, c = threadIdx.x;
    const float* W = preW + (size_t)l * 384 * 128 + 256 * 128;
    float acc = preB[l * 128 + c];
    #pragma unroll 4
    for (int k = 0; k < EMB; ++k) acc += bs[code * EMB + k] * W[k * 128 + c];
    Tb[(size_t)(l * 64 + code) * 128 + c] = f2b(acc);
}

// ---------------- weight packing into MFMA B-fragment layout ----------------
// B frag elem linear index: ((ks*NT + nt)*64 + lane)*8 + j
// maps to B[k = ks*32 + (lane>>4)*8 + j][n = nt*16 + (lane&15)]

__global__ void pack_wb(const float* __restrict__ preW, bf16* __restrict__ out) {
    int idx = blockIdx.x * 256 + threadIdx.x;
    if (idx >= DEPTH * 32768) return;
    int j = idx & 7, L = (idx >> 3) & 63, nt = (idx >> 9) & 15, ks = (idx >> 13) & 3, l = idx >> 15;
    int k = ks * 32 + ((L >> 4) * 8) + j;
    int n = nt * 16 + (L & 15);
    const float* W = preW + (size_t)l * 384 * 128;
    float v = (n < 128) ? W[k * 128 + n] : W[(128 + k) * 128 + (n - 128)];
    out[idx] = f2b(v);
}

__global__ void pack_wc(const float* __restrict__ postW, bf16* __restrict__ out) {
    int idx = blockIdx.x * 256 + threadIdx.x;
    if (idx >= DEPTH * 81920) return;
    int j = idx & 7, L = (idx >> 3) & 63, nt = (idx >> 9) & 7;
    int t = idx >> 12;
    int ks = t % 20, l = t / 20;
    int k = ks * 32 + ((L >> 4) * 8) + j;
    int n = nt * 16 + (L & 15);
    const float* W = postW + (size_t)l * 1664 * 128;
    float v;
    if (k < 128) {
        v = W[k * 128 + n];
    } else {
        int jj = k - 128;
        v = W[(128 + jj) * 128 + n] + LOG7 * W[(640 + jj) * 128 + n] + ILOG7 * W[(1152 + jj) * 128 + n];
    }
    out[idx] = f2b(v);
}

// WrB[l]: Wr[16,128] (= preW rows 368:384) as B-frags, K padded to 32 with zeros.
// idx = (l*8 + nt)*64*8 + lane*8 + j ; k=(lane>>4)*8+j (valid k<16), n=nt*16+(lane&15)
__global__ void pack_wr(const float* __restrict__ preW, bf16* __restrict__ out) {
    int idx = blockIdx.x * 256 + threadIdx.x;
    if (idx >= DEPTH * 4096) return;
    int j = idx & 7, L = (idx >> 3) & 63, nt = (idx >> 9) & 7, l = idx >> 12;
    int k = ((L >> 4) * 8) + j;
    int n = nt * 16 + (L & 15);
    float v = (k < 16) ? preW[(size_t)l * 384 * 128 + (368 + k) * 128 + n] : 0.f;
    out[idx] = f2b(v);
}

// ---------------- layer-0 Z12 GEMM: z12 = h @ wb0 ----------------
__global__ __launch_bounds__(256) void gemm_z12(const bf16* __restrict__ A,
                                                const bf16* __restrict__ Bp,
                                                bf16* __restrict__ C) {
    int lane = threadIdx.x & 63;
    int wave = threadIdx.x >> 6;
    int m = lane & 15, quad = lane >> 4;
    int row0 = blockIdx.x * 64 + wave * 16;

    frag_cd acc[16];
    #pragma unroll
    for (int nt = 0; nt < 16; ++nt)
        #pragma unroll
        for (int i = 0; i < 4; ++i) acc[nt][i] = 0.f;

    const frag_ab* Bf = (const frag_ab*)Bp;
    const bf16* arow = A + (size_t)(row0 + m) * 128;
    #pragma unroll
    for (int ks = 0; ks < 4; ++ks) {
        frag_ab a = *(const frag_ab*)(arow + ks * 32 + quad * 8);
        #pragma unroll
        for (int nt = 0; nt < 16; ++nt) {
            frag_ab b = Bf[(ks * 16 + nt) * 64 + lane];
            acc[nt] = __builtin_amdgcn_mfma_f32_16x16x32_bf16(a, b, acc[nt], 0, 0, 0);
        }
    }
    #pragma unroll
    for (int nt = 0; nt < 16; ++nt) {
        int col = nt * 16 + m;
        #pragma unroll
        for (int r = 0; r < 4; ++r) {
            int row = row0 + quad * 4 + r;
            C[(size_t)row * 256 + col] = f2b(acc[nt][r]);
        }
    }
}

// ---------------- fused posttrans + residual + next-layer Z12 ----------------
// 64-row tile, 512 threads / 8 waves: wave = (rt 0..3, nh 0..1). grid = N/64 = 512.
__global__ __launch_bounds__(512) void layer_k(bf16* __restrict__ h,       // bf16 state, in-place
                                               const bf16* __restrict__ aggc,
                                               const bf16* __restrict__ Bp,
                                               const float* __restrict__ bias,
                                               const bf16* __restrict__ Bn,
                                               bf16* __restrict__ z12) {
    __shared__ __align__(16) bf16 newh[64 * 136];   // pad 136: b128-aligned rows
    int lane = threadIdx.x & 63;
    int wave = threadIdx.x >> 6;
    int rt = wave & 3;        // row-tile
    int nh = wave >> 2;       // col-half
    int m = lane & 15, quad = lane >> 4;
    int row0 = blockIdx.x * 64;
    int rowA = row0 + rt * 16 + m;

    frag_cd acc[4];
    #pragma unroll
    for (int nt = 0; nt < 4; ++nt)
        #pragma unroll
        for (int i = 0; i < 4; ++i) acc[nt][i] = 0.f;

    const frag_ab* Bf = (const frag_ab*)Bp;
    const bf16* arow = h + (size_t)rowA * 128;
    #pragma unroll
    for (int ks = 0; ks < 4; ++ks) {
        frag_ab a = *(const frag_ab*)(arow + ks * 32 + quad * 8);
        #pragma unroll
        for (int nt = 0; nt < 4; ++nt) {
            frag_ab b = Bf[(ks * 8 + nh * 4 + nt) * 64 + lane];
            acc[nt] = __builtin_amdgcn_mfma_f32_16x16x32_bf16(a, b, acc[nt], 0, 0, 0);
        }
    }
    const bf16* grow = aggc + (size_t)rowA * 512;
    #pragma unroll
    for (int ks = 0; ks < 16; ++ks) {
        frag_ab a = *(const frag_ab*)(grow + ks * 32 + quad * 8);
        #pragma unroll
        for (int nt = 0; nt < 4; ++nt) {
            frag_ab b = Bf[((4 + ks) * 8 + nh * 4 + nt) * 64 + lane];
            acc[nt] = __builtin_amdgcn_mfma_f32_16x16x32_bf16(a, b, acc[nt], 0, 0, 0);
        }
    }

    __syncthreads();   // all waves done reading h rows before any in-place write

    #pragma unroll
    for (int nt = 0; nt < 4; ++nt) {
        int col = nh * 64 + nt * 16 + m;
        float bs_ = bias[col];
        #pragma unroll
        for (int r = 0; r < 4; ++r) {
            int lr = rt * 16 + quad * 4 + r;
            int row = row0 + lr;
            float nv = acc[nt][r] + bs_ + b2f(h[(size_t)row * HID + col]);
            bf16 bv = f2b(nv);
            h[(size_t)row * HID + col] = bv;
            newh[lr * 136 + col] = bv;
        }
    }

    if (Bn) {
        __syncthreads();
        const frag_ab* Bf2 = (const frag_ab*)Bn;
        frag_cd a2[8];
        #pragma unroll
        for (int nt = 0; nt < 8; ++nt)
            #pragma unroll
            for (int i = 0; i < 4; ++i) a2[nt][i] = 0.f;
        #pragma unroll
        for (int ks = 0; ks < 4; ++ks) {
            frag_ab a = *(const frag_ab*)&newh[(rt * 16 + m) * 136 + ks * 32 + quad * 8];
            #pragma unroll
            for (int nt = 0; nt < 8; ++nt) {
                frag_ab b = Bf2[(ks * 16 + nh * 8 + nt) * 64 + lane];
                a2[nt] = __builtin_amdgcn_mfma_f32_16x16x32_bf16(a, b, a2[nt], 0, 0, 0);
            }
        }
        #pragma unroll
        for (int nt = 0; nt < 8; ++nt) {
            int col = nh * 128 + nt * 16 + m;
            #pragma unroll
            for (int r = 0; r < 4; ++r) {
                int row = row0 + rt * 16 + quad * 4 + r;
                z12[(size_t)row * 256 + col] = f2b(a2[nt][r]);
            }
        }
    }
}

// ---------------- fused edge-transform + aggregation ----------------
// Phase 0: rdot[48,128] = rnd[48,16] @ Wr via MFMA (3 waves x 8 n-tiles, K=16 zero-padded)
// Phase A: val = z1[src] + z2 + Tb[code] + rdot ; agg -> aggc
__global__ __launch_bounds__(256) void fused_agg(const bf16* __restrict__ Z12,
                                                 const int* __restrict__ src,
                                                 const unsigned char* __restrict__ code,
                                                 const float* __restrict__ rand_edge,
                                                 const bf16* __restrict__ Tb,
                                                 const bf16* __restrict__ WrB,
                                                 bf16* __restrict__ aggc) {
    __shared__ __align__(16) float rdot[48 * 130];   // 24.4 KB; stride 130: quad rows land on banks +8 apart
    int tid = threadIdx.x;
    int lane = tid & 63, wave = tid >> 6;
    int bv = blockIdx.x * 8;

    // ---- phase 0 ----
    if (wave < 3) {
        int m = lane & 15, quad = lane >> 4;
        frag_ab a;
        if (quad < 2) {
            const float4* rp = (const float4*)(rand_edge
                + ((size_t)blockIdx.x * 48 + wave * 16 + m) * 16 + quad * 8);
            float4 A = rp[0], B = rp[1];
            a[0] = f2s(A.x); a[1] = f2s(A.y); a[2] = f2s(A.z); a[3] = f2s(A.w);
            a[4] = f2s(B.x); a[5] = f2s(B.y); a[6] = f2s(B.z); a[7] = f2s(B.w);
        } else {
            #pragma unroll
            for (int j = 0; j < 8; ++j) a[j] = 0;
        }
        const frag_ab* Bf = (const frag_ab*)WrB;
        #pragma unroll
        for (int nt = 0; nt < 8; ++nt) {
            frag_cd acc;
            #pragma unroll
            for (int i = 0; i < 4; ++i) acc[i] = 0.f;
            acc = __builtin_amdgcn_mfma_f32_16x16x32_bf16(a, Bf[nt * 64 + lane], acc, 0, 0, 0);
            #pragma unroll
            for (int r = 0; r < 4; ++r)
                rdot[(wave * 16 + quad * 4 + r) * 130 + nt * 16 + m] = acc[r];
        }
    }
    __syncthreads();

    // ---- phase A ----
    int c = tid & 127, half = tid >> 7;
    #pragma unroll
    for (int i = 0; i < 4; ++i) {
        int nb = half * 4 + i;
        int v = bv + nb;
        float z2 = b2f(Z12[(size_t)v * 256 + 128 + c]);
        const int2* sp = (const int2*)(src + v * 6);
        int2 s01 = sp[0], s23 = sp[1], s45 = sp[2];
        const unsigned short* cp = (const unsigned short*)(code + v * 6);
        unsigned short c01 = cp[0], c23 = cp[1], c45 = cp[2];
        int svs[6] = { s01.x, s01.y, s23.x, s23.y, s45.x, s45.y };
        int cds[6] = { c01 & 255, c01 >> 8, c23 & 255, c23 >> 8, c45 & 255, c45 >> 8 };
        float z1[6], tv[6];
        #pragma unroll
        for (int j = 0; j < 6; ++j) z1[j] = b2f(Z12[(size_t)svs[j] * 256 + c]);
        #pragma unroll
        for (int j = 0; j < 6; ++j) tv[j] = b2f(Tb[cds[j] * 128 + c]);
        float s = 0.f, ss = 0.f, mx = -1e30f, mn = 1e30f;
        #pragma unroll
        for (int j = 0; j < 6; ++j) {
            float val = z1[j] + z2 + tv[j] + rdot[(nb * 6 + j) * 130 + c];
            val = fmaxf(val, 0.f);
            s += val; ss += val * val; mx = fmaxf(mx, val); mn = fminf(mn, val);
        }
        float mean = s * (1.f / 6.f);
        float msq = ss * (1.f / 6.f);
        float sd = sqrtf(fmaxf(msq - mean * mean, 0.f) + 1e-5f);
        size_t base = (size_t)v * 512;
        aggc[base + c]       = f2b(mean);
        aggc[base + 128 + c] = f2b(mx);
        aggc[base + 256 + c] = f2b(mn);
        aggc[base + 384 + c] = f2b(sd);
    }
}

// ---------------- readout ----------------
__global__ __launch_bounds__(128) void readout(const bf16* __restrict__ h, const float* __restrict__ W1,
                                               const float* __restrict__ b1, const float* __restrict__ W2,
                                               const float* __restrict__ b2, float* __restrict__ out) {
    __shared__ float r[384];
    __shared__ float y1[128];
    int g = blockIdx.x, c = threadIdx.x;
    float s = 0.f, mx = -1e30f;
    for (int v = 0; v < 128; ++v) {
        float hv = b2f(h[((size_t)g * 128 + v) * HID + c]);
        s += hv; mx = fmaxf(mx, hv);
    }
    r[c] = s * (1.f / 128.f);
    r[128 + c] = s;
    r[256 + c] = mx;
    __syncthreads();
    float a1 = b1[c];
    for (int k = 0; k < 384; ++k) a1 += r[k] * W1[k * 128 + c];
    y1[c] = fmaxf(a1, 0.f);
    __syncthreads();
    #pragma unroll
    for (int o = 0; o < 2; ++o) {
        int t = c + o * 128;
        float a2 = b2[t];
        for (int k = 0; k < 128; ++k) a2 += y1[k] * W2[k * 256 + t];
        out[(size_t)g * 256 + t] = a2;
    }
}

// ---------------- launch ----------------
extern "C" void kernel_launch(void* const* d_in, const int* in_sizes, int n_in,
                              void* d_out, int out_size, void* d_ws, size_t ws_size,
                              hipStream_t stream) {
    const int*   atom_feats = (const int*)d_in[0];
    const int*   bond_feats = (const int*)d_in[1];
    const int*   src        = (const int*)d_in[2];
    const float* rand_x     = (const float*)d_in[6];
    const float* rand_edge  = (const float*)d_in[7];
    const float* atom_emb   = (const float*)d_in[8];
    const float* bond_emb   = (const float*)d_in[9];
    const float* pre_W      = (const float*)d_in[10];
    const float* pre_b      = (const float*)d_in[11];
    const float* post_W     = (const float*)d_in[12];
    const float* post_b     = (const float*)d_in[13];
    const float* ro_W1      = (const float*)d_in[14];
    const float* ro_b1      = (const float*)d_in[15];
    const float* ro_W2      = (const float*)d_in[16];
    const float* ro_b2      = (const float*)d_in[17];

    char* p = (char*)d_ws;
    auto alloc = [&](size_t bytes) {
        char* r = p;
        p += (bytes + 255) & ~(size_t)255;
        return r;
    };
    bf16*  h    = (bf16*) alloc((size_t)N_NODES * HID * 2);      // 8 MB (bf16 state)
    bf16*  z12  = (bf16*) alloc((size_t)N_NODES * 256 * 2);      // 16 MB
    bf16*  aggc = (bf16*) alloc((size_t)N_NODES * 512 * 2);      // 32 MB
    bf16*  wb   = (bf16*) alloc((size_t)DEPTH * 32768 * 2);
    bf16*  wc   = (bf16*) alloc((size_t)DEPTH * 81920 * 2);
    bf16*  wrB  = (bf16*) alloc((size_t)DEPTH * 4096 * 2);       // 40 KB
    bf16*  Tb   = (bf16*) alloc((size_t)DEPTH * 64 * 128 * 2);   // 80 KB
    float* bs   = (float*)alloc((size_t)64 * EMB * 4);           // 28 KB
    unsigned char* code = (unsigned char*)alloc(N_EDGES);        // 192 KB

    pack_wb<<<(DEPTH * 32768 + 255) / 256, 256, 0, stream>>>(pre_W, wb);
    pack_wc<<<(DEPTH * 81920 + 255) / 256, 256, 0, stream>>>(post_W, wc);
    pack_wr<<<(DEPTH * 4096 + 255) / 256, 256, 0, stream>>>(pre_W, wrB);
    bond_code_k<<<(N_EDGES + 255) / 256, 256, 0, stream>>>(bond_feats, code);
    bond_sum_k<<<64, EMB, 0, stream>>>(bond_emb, bs);
    bond_T_k<<<DEPTH * 64, 128, 0, stream>>>(bs, pre_W, pre_b, Tb);

    encode_nodes<<<N_NODES, 128, 0, stream>>>(atom_feats, rand_x, atom_emb, h);

    // layer-0 Z12
    gemm_z12<<<N_NODES / 64, 256, 0, stream>>>(h, wb, z12);

    for (int l = 0; l < DEPTH; ++l) {
        fused_agg<<<N_NODES / 8, 256, 0, stream>>>(
            z12, src, code, rand_edge,
            Tb + (size_t)l * 8192,
            wrB + (size_t)l * 4096, aggc);
        const bf16* wbn = (l + 1 < DEPTH) ? (wb + (size_t)(l + 1) * 32768) : nullptr;
        layer_k<<<N_NODES / 64, 512, 0, stream>>>(
            h, aggc, wc + (size_t)l * 81920, post_b + l * HID, wbn, z12);
    }

    readout<<<N_GRAPHS, 128, 0, stream>>>(h, ro_W1, ro_b1, ro_W2, ro_b2, (float*)d_out);
}

// Round 11
// 389.467 us; speedup vs baseline: 1.8048x; 1.0457x over previous
//
#include <hip/hip_runtime.h>
#include <hip/hip_bf16.h>

#define N_NODES 32768
#define N_EDGES 196608
#define N_GRAPHS 256
#define DEG 6
#define HID 128
#define RVD 16
#define EMB 112
#define VOCAB 128
#define TGT 256
#define DEPTH 5

#define LOG7 1.9459101090932196f
#define ILOG7 0.5138983423697507f

typedef __hip_bfloat16 bf16;
using frag_ab = __attribute__((ext_vector_type(8))) short;   // 8 bf16
using frag_cd = __attribute__((ext_vector_type(4))) float;   // 4 f32

static __device__ __forceinline__ float b2f(bf16 x) { return __bfloat162float(x); }
static __device__ __forceinline__ bf16  f2b(float x) { return __float2bfloat16(x); }
static __device__ __forceinline__ short f2s(float x) {
    bf16 b = __float2bfloat16(x);
    return *reinterpret_cast<short*>(&b);
}
static __device__ __forceinline__ float us2f(unsigned short u) {
    unsigned int x = ((unsigned int)u) << 16;
    return __uint_as_float(x);
}
static __device__ __forceinline__ unsigned short f2us(float x) {
    bf16 b = __float2bfloat16(x);
    return *reinterpret_cast<unsigned short*>(&b);
}

// ---------------- encoders ----------------
__global__ void encode_nodes(const int* __restrict__ af, const float* __restrict__ rx,
                             const float* __restrict__ emb, bf16* __restrict__ h) {
    int v = blockIdx.x, c = threadIdx.x;
    float val;
    if (c < EMB) {
        val = 0.f;
        #pragma unroll
        for (int i = 0; i < 9; ++i) {
            int f = af[v * 9 + i];
            val += emb[(i * VOCAB + f) * EMB + c];
        }
    } else {
        val = rx[v * RVD + (c - EMB)];
    }
    h[(size_t)v * HID + c] = f2b(val);
}

// ---------------- bond factorization ----------------
__global__ void bond_code_k(const int* __restrict__ bfeat, unsigned char* __restrict__ code) {
    int e = blockIdx.x * 256 + threadIdx.x;
    if (e < N_EDGES)
        code[e] = (unsigned char)(bfeat[e * 3] | (bfeat[e * 3 + 1] << 2) | (bfeat[e * 3 + 2] << 4));
}

__global__ void bond_sum_k(const float* __restrict__ bemb, float* __restrict__ bs) {
    int code = blockIdx.x, k = threadIdx.x;   // 64 blocks x 112
    int f0 = code & 3, f1 = (code >> 2) & 3, f2 = code >> 4;
    bs[code * EMB + k] = bemb[(0 * VOCAB + f0) * EMB + k]
                       + bemb[(1 * VOCAB + f1) * EMB + k]
                       + bemb[(2 * VOCAB + f2) * EMB + k];
}

// Tb[l][code][c] = bondsum[code] @ preW[l][256:368][c] + pre_b[l][c]   (bf16 table, bias folded)
__global__ void bond_T_k(const float* __restrict__ bs, const float* __restrict__ preW,
                         const float* __restrict__ preB, bf16* __restrict__ Tb) {
    int l = blockIdx.x >> 6, code = blockIdx.x & 63, c = threadIdx.x;
    const float* W = preW + (size_t)l * 384 * 128 + 256 * 128;
    float acc = preB[l * 128 + c];
    #pragma unroll 4
    for (int k = 0; k < EMB; ++k) acc += bs[code * EMB + k] * W[k * 128 + c];
    Tb[(size_t)(l * 64 + code) * 128 + c] = f2b(acc);
}

// ---------------- weight packing into MFMA B-fragment layout ----------------
// B frag elem linear index: ((ks*NT + nt)*64 + lane)*8 + j
// maps to B[k = ks*32 + (lane>>4)*8 + j][n = nt*16 + (lane&15)]

__global__ void pack_wb(const float* __restrict__ preW, bf16* __restrict__ out) {
    int idx = blockIdx.x * 256 + threadIdx.x;
    if (idx >= DEPTH * 32768) return;
    int j = idx & 7, L = (idx >> 3) & 63, nt = (idx >> 9) & 15, ks = (idx >> 13) & 3, l = idx >> 15;
    int k = ks * 32 + ((L >> 4) * 8) + j;
    int n = nt * 16 + (L & 15);
    const float* W = preW + (size_t)l * 384 * 128;
    float v = (n < 128) ? W[k * 128 + n] : W[(128 + k) * 128 + (n - 128)];
    out[idx] = f2b(v);
}

__global__ void pack_wc(const float* __restrict__ postW, bf16* __restrict__ out) {
    int idx = blockIdx.x * 256 + threadIdx.x;
    if (idx >= DEPTH * 81920) return;
    int j = idx & 7, L = (idx >> 3) & 63, nt = (idx >> 9) & 7;
    int t = idx >> 12;
    int ks = t % 20, l = t / 20;
    int k = ks * 32 + ((L >> 4) * 8) + j;
    int n = nt * 16 + (L & 15);
    const float* W = postW + (size_t)l * 1664 * 128;
    float v;
    if (k < 128) {
        v = W[k * 128 + n];
    } else {
        int jj = k - 128;
        v = W[(128 + jj) * 128 + n] + LOG7 * W[(640 + jj) * 128 + n] + ILOG7 * W[(1152 + jj) * 128 + n];
    }
    out[idx] = f2b(v);
}

// WrB[l]: Wr[16,128] (= preW rows 368:384) as B-frags, K padded to 32 with zeros.
__global__ void pack_wr(const float* __restrict__ preW, bf16* __restrict__ out) {
    int idx = blockIdx.x * 256 + threadIdx.x;
    if (idx >= DEPTH * 4096) return;
    int j = idx & 7, L = (idx >> 3) & 63, nt = (idx >> 9) & 7, l = idx >> 12;
    int k = ((L >> 4) * 8) + j;
    int n = nt * 16 + (L & 15);
    float v = (k < 16) ? preW[(size_t)l * 384 * 128 + (368 + k) * 128 + n] : 0.f;
    out[idx] = f2b(v);
}

// ---------------- layer-0 Z12 GEMM: z12 = h @ wb0 ----------------
__global__ __launch_bounds__(256) void gemm_z12(const bf16* __restrict__ A,
                                                const bf16* __restrict__ Bp,
                                                bf16* __restrict__ C) {
    int lane = threadIdx.x & 63;
    int wave = threadIdx.x >> 6;
    int m = lane & 15, quad = lane >> 4;
    int row0 = blockIdx.x * 64 + wave * 16;

    frag_cd acc[16];
    #pragma unroll
    for (int nt = 0; nt < 16; ++nt)
        #pragma unroll
        for (int i = 0; i < 4; ++i) acc[nt][i] = 0.f;

    const frag_ab* Bf = (const frag_ab*)Bp;
    const bf16* arow = A + (size_t)(row0 + m) * 128;
    #pragma unroll
    for (int ks = 0; ks < 4; ++ks) {
        frag_ab a = *(const frag_ab*)(arow + ks * 32 + quad * 8);
        #pragma unroll
        for (int nt = 0; nt < 16; ++nt) {
            frag_ab b = Bf[(ks * 16 + nt) * 64 + lane];
            acc[nt] = __builtin_amdgcn_mfma_f32_16x16x32_bf16(a, b, acc[nt], 0, 0, 0);
        }
    }
    #pragma unroll
    for (int nt = 0; nt < 16; ++nt) {
        int col = nt * 16 + m;
        #pragma unroll
        for (int r = 0; r < 4; ++r) {
            int row = row0 + quad * 4 + r;
            C[(size_t)row * 256 + col] = f2b(acc[nt][r]);
        }
    }
}

// ---------------- fused posttrans + residual + next-layer Z12 ----------------
// 64-row tile, 512 threads / 8 waves: wave = (rt 0..3, nh 0..1). grid = N/64 = 512.
__global__ __launch_bounds__(512) void layer_k(bf16* __restrict__ h,       // bf16 state, in-place
                                               const bf16* __restrict__ aggc,
                                               const bf16* __restrict__ Bp,
                                               const float* __restrict__ bias,
                                               const bf16* __restrict__ Bn,
                                               bf16* __restrict__ z12) {
    __shared__ __align__(16) bf16 newh[64 * 136];   // pad 136: b128-aligned rows
    int lane = threadIdx.x & 63;
    int wave = threadIdx.x >> 6;
    int rt = wave & 3;        // row-tile
    int nh = wave >> 2;       // col-half
    int m = lane & 15, quad = lane >> 4;
    int row0 = blockIdx.x * 64;
    int rowA = row0 + rt * 16 + m;

    frag_cd acc[4];
    #pragma unroll
    for (int nt = 0; nt < 4; ++nt)
        #pragma unroll
        for (int i = 0; i < 4; ++i) acc[nt][i] = 0.f;

    const frag_ab* Bf = (const frag_ab*)Bp;
    const bf16* arow = h + (size_t)rowA * 128;
    #pragma unroll
    for (int ks = 0; ks < 4; ++ks) {
        frag_ab a = *(const frag_ab*)(arow + ks * 32 + quad * 8);
        #pragma unroll
        for (int nt = 0; nt < 4; ++nt) {
            frag_ab b = Bf[(ks * 8 + nh * 4 + nt) * 64 + lane];
            acc[nt] = __builtin_amdgcn_mfma_f32_16x16x32_bf16(a, b, acc[nt], 0, 0, 0);
        }
    }
    const bf16* grow = aggc + (size_t)rowA * 512;
    #pragma unroll
    for (int ks = 0; ks < 16; ++ks) {
        frag_ab a = *(const frag_ab*)(grow + ks * 32 + quad * 8);
        #pragma unroll
        for (int nt = 0; nt < 4; ++nt) {
            frag_ab b = Bf[((4 + ks) * 8 + nh * 4 + nt) * 64 + lane];
            acc[nt] = __builtin_amdgcn_mfma_f32_16x16x32_bf16(a, b, acc[nt], 0, 0, 0);
        }
    }

    __syncthreads();   // all waves done reading h rows before any in-place write

    #pragma unroll
    for (int nt = 0; nt < 4; ++nt) {
        int col = nh * 64 + nt * 16 + m;
        float bs_ = bias[col];
        #pragma unroll
        for (int r = 0; r < 4; ++r) {
            int lr = rt * 16 + quad * 4 + r;
            int row = row0 + lr;
            float nv = acc[nt][r] + bs_ + b2f(h[(size_t)row * HID + col]);
            bf16 bv = f2b(nv);
            h[(size_t)row * HID + col] = bv;
            newh[lr * 136 + col] = bv;
        }
    }

    if (Bn) {
        __syncthreads();
        const frag_ab* Bf2 = (const frag_ab*)Bn;
        frag_cd a2[8];
        #pragma unroll
        for (int nt = 0; nt < 8; ++nt)
            #pragma unroll
            for (int i = 0; i < 4; ++i) a2[nt][i] = 0.f;
        #pragma unroll
        for (int ks = 0; ks < 4; ++ks) {
            frag_ab a = *(const frag_ab*)&newh[(rt * 16 + m) * 136 + ks * 32 + quad * 8];
            #pragma unroll
            for (int nt = 0; nt < 8; ++nt) {
                frag_ab b = Bf2[(ks * 16 + nh * 8 + nt) * 64 + lane];
                a2[nt] = __builtin_amdgcn_mfma_f32_16x16x32_bf16(a, b, a2[nt], 0, 0, 0);
            }
        }
        #pragma unroll
        for (int nt = 0; nt < 8; ++nt) {
            int col = nh * 128 + nt * 16 + m;
            #pragma unroll
            for (int r = 0; r < 4; ++r) {
                int row = row0 + rt * 16 + quad * 4 + r;
                z12[(size_t)row * 256 + col] = f2b(a2[nt][r]);
            }
        }
    }
}

// ---------------- fused edge-transform + aggregation ----------------
// Phase 0: rdot[48,128] = rnd[48,16] @ Wr via MFMA (3 waves x 8 n-tiles, K=16 zero-padded)
// Phase A: 2 channels/thread, all gathers ushort2 (4B): 64 threads/node-row.
__global__ __launch_bounds__(256) void fused_agg(const bf16* __restrict__ Z12,
                                                 const int* __restrict__ src,
                                                 const unsigned char* __restrict__ code,
                                                 const float* __restrict__ rand_edge,
                                                 const bf16* __restrict__ Tb,
                                                 const bf16* __restrict__ WrB,
                                                 bf16* __restrict__ aggc) {
    __shared__ __align__(16) float rdot[48 * 130];   // 24.4 KB; stride 130 spreads quad rows across banks
    int tid = threadIdx.x;
    int lane = tid & 63, wave = tid >> 6;
    int bv = blockIdx.x * 8;

    // ---- phase 0 ----
    if (wave < 3) {
        int m = lane & 15, quad = lane >> 4;
        frag_ab a;
        if (quad < 2) {
            const float4* rp = (const float4*)(rand_edge
                + ((size_t)blockIdx.x * 48 + wave * 16 + m) * 16 + quad * 8);
            float4 A = rp[0], B = rp[1];
            a[0] = f2s(A.x); a[1] = f2s(A.y); a[2] = f2s(A.z); a[3] = f2s(A.w);
            a[4] = f2s(B.x); a[5] = f2s(B.y); a[6] = f2s(B.z); a[7] = f2s(B.w);
        } else {
            #pragma unroll
            for (int j = 0; j < 8; ++j) a[j] = 0;
        }
        const frag_ab* Bf = (const frag_ab*)WrB;
        #pragma unroll
        for (int nt = 0; nt < 8; ++nt) {
            frag_cd acc;
            #pragma unroll
            for (int i = 0; i < 4; ++i) acc[i] = 0.f;
            acc = __builtin_amdgcn_mfma_f32_16x16x32_bf16(a, Bf[nt * 64 + lane], acc, 0, 0, 0);
            #pragma unroll
            for (int r = 0; r < 4; ++r)
                rdot[(wave * 16 + quad * 4 + r) * 130 + nt * 16 + m] = acc[r];
        }
    }
    __syncthreads();

    // ---- phase A: 2 channels per thread, 64 threads per node ----
    const unsigned short* Zu = (const unsigned short*)Z12;
    const unsigned short* Tu = (const unsigned short*)Tb;
    unsigned short* Au = (unsigned short*)aggc;
    int c = lane * 2;          // even channel pair
    int g = wave;              // node group 0..3, 2 nodes each

    #pragma unroll
    for (int i = 0; i < 2; ++i) {
        int nb = g * 2 + i;
        int v = bv + nb;
        ushort2 z2u = *(const ushort2*)(Zu + (size_t)v * 256 + 128 + c);
        float z2a = us2f(z2u.x), z2b = us2f(z2u.y);
        const int2* sp = (const int2*)(src + v * 6);
        int2 s01 = sp[0], s23 = sp[1], s45 = sp[2];
        const unsigned short* cp = (const unsigned short*)(code + v * 6);
        unsigned short c01 = cp[0], c23 = cp[1], c45 = cp[2];
        int svs[6] = { s01.x, s01.y, s23.x, s23.y, s45.x, s45.y };
        int cds[6] = { c01 & 255, c01 >> 8, c23 & 255, c23 >> 8, c45 & 255, c45 >> 8 };
        ushort2 z1u[6], tvu[6];
        #pragma unroll
        for (int j = 0; j < 6; ++j) z1u[j] = *(const ushort2*)(Zu + (size_t)svs[j] * 256 + c);
        #pragma unroll
        for (int j = 0; j < 6; ++j) tvu[j] = *(const ushort2*)(Tu + cds[j] * 128 + c);
        float sa = 0.f, ssa = 0.f, mxa = -1e30f, mna = 1e30f;
        float sb = 0.f, ssb = 0.f, mxb = -1e30f, mnb = 1e30f;
        #pragma unroll
        for (int j = 0; j < 6; ++j) {
            const float2 rd = *(const float2*)(rdot + (nb * 6 + j) * 130 + c);
            float va = us2f(z1u[j].x) + z2a + us2f(tvu[j].x) + rd.x;
            float vb = us2f(z1u[j].y) + z2b + us2f(tvu[j].y) + rd.y;
            va = fmaxf(va, 0.f);
            vb = fmaxf(vb, 0.f);
            sa += va; ssa += va * va; mxa = fmaxf(mxa, va); mna = fminf(mna, va);
            sb += vb; ssb += vb * vb; mxb = fmaxf(mxb, vb); mnb = fminf(mnb, vb);
        }
        float meana = sa * (1.f / 6.f), meanb = sb * (1.f / 6.f);
        float msqa = ssa * (1.f / 6.f), msqb = ssb * (1.f / 6.f);
        float sda = sqrtf(fmaxf(msqa - meana * meana, 0.f) + 1e-5f);
        float sdb = sqrtf(fmaxf(msqb - meanb * meanb, 0.f) + 1e-5f);
        size_t base = (size_t)v * 512 + c;
        *(ushort2*)(Au + base)       = make_ushort2(f2us(meana), f2us(meanb));
        *(ushort2*)(Au + base + 128) = make_ushort2(f2us(mxa),  f2us(mxb));
        *(ushort2*)(Au + base + 256) = make_ushort2(f2us(mna),  f2us(mnb));
        *(ushort2*)(Au + base + 384) = make_ushort2(f2us(sda),  f2us(sdb));
    }
}

// ---------------- readout ----------------
__global__ __launch_bounds__(128) void readout(const bf16* __restrict__ h, const float* __restrict__ W1,
                                               const float* __restrict__ b1, const float* __restrict__ W2,
                                               const float* __restrict__ b2, float* __restrict__ out) {
    __shared__ float r[384];
    __shared__ float y1[128];
    int g = blockIdx.x, c = threadIdx.x;
    float s = 0.f, mx = -1e30f;
    for (int v = 0; v < 128; ++v) {
        float hv = b2f(h[((size_t)g * 128 + v) * HID + c]);
        s += hv; mx = fmaxf(mx, hv);
    }
    r[c] = s * (1.f / 128.f);
    r[128 + c] = s;
    r[256 + c] = mx;
    __syncthreads();
    float a1 = b1[c];
    for (int k = 0; k < 384; ++k) a1 += r[k] * W1[k * 128 + c];
    y1[c] = fmaxf(a1, 0.f);
    __syncthreads();
    #pragma unroll
    for (int o = 0; o < 2; ++o) {
        int t = c + o * 128;
        float a2 = b2[t];
        for (int k = 0; k < 128; ++k) a2 += y1[k] * W2[k * 256 + t];
        out[(size_t)g * 256 + t] = a2;
    }
}

// ---------------- launch ----------------
extern "C" void kernel_launch(void* const* d_in, const int* in_sizes, int n_in,
                              void* d_out, int out_size, void* d_ws, size_t ws_size,
                              hipStream_t stream) {
    const int*   atom_feats = (const int*)d_in[0];
    const int*   bond_feats = (const int*)d_in[1];
    const int*   src        = (const int*)d_in[2];
    const float* rand_x     = (const float*)d_in[6];
    const float* rand_edge  = (const float*)d_in[7];
    const float* atom_emb   = (const float*)d_in[8];
    const float* bond_emb   = (const float*)d_in[9];
    const float* pre_W      = (const float*)d_in[10];
    const float* pre_b      = (const float*)d_in[11];
    const float* post_W     = (const float*)d_in[12];
    const float* post_b     = (const float*)d_in[13];
    const float* ro_W1      = (const float*)d_in[14];
    const float* ro_b1      = (const float*)d_in[15];
    const float* ro_W2      = (const float*)d_in[16];
    const float* ro_b2      = (const float*)d_in[17];

    char* p = (char*)d_ws;
    auto alloc = [&](size_t bytes) {
        char* r = p;
        p += (bytes + 255) & ~(size_t)255;
        return r;
    };
    bf16*  h    = (bf16*) alloc((size_t)N_NODES * HID * 2);      // 8 MB (bf16 state)
    bf16*  z12  = (bf16*) alloc((size_t)N_NODES * 256 * 2);      // 16 MB
    bf16*  aggc = (bf16*) alloc((size_t)N_NODES * 512 * 2);      // 32 MB
    bf16*  wb   = (bf16*) alloc((size_t)DEPTH * 32768 * 2);
    bf16*  wc   = (bf16*) alloc((size_t)DEPTH * 81920 * 2);
    bf16*  wrB  = (bf16*) alloc((size_t)DEPTH * 4096 * 2);       // 40 KB
    bf16*  Tb   = (bf16*) alloc((size_t)DEPTH * 64 * 128 * 2);   // 80 KB
    float* bs   = (float*)alloc((size_t)64 * EMB * 4);           // 28 KB
    unsigned char* code = (unsigned char*)alloc(N_EDGES);        // 192 KB

    pack_wb<<<(DEPTH * 32768 + 255) / 256, 256, 0, stream>>>(pre_W, wb);
    pack_wc<<<(DEPTH * 81920 + 255) / 256, 256, 0, stream>>>(post_W, wc);
    pack_wr<<<(DEPTH * 4096 + 255) / 256, 256, 0, stream>>>(pre_W, wrB);
    bond_code_k<<<(N_EDGES + 255) / 256, 256, 0, stream>>>(bond_feats, code);
    bond_sum_k<<<64, EMB, 0, stream>>>(bond_emb, bs);
    bond_T_k<<<DEPTH * 64, 128, 0, stream>>>(bs, pre_W, pre_b, Tb);

    encode_nodes<<<N_NODES, 128, 0, stream>>>(atom_feats, rand_x, atom_emb, h);

    // layer-0 Z12
    gemm_z12<<<N_NODES / 64, 256, 0, stream>>>(h, wb, z12);

    for (int l = 0; l < DEPTH; ++l) {
        fused_agg<<<N_NODES / 8, 256, 0, stream>>>(
            z12, src, code, rand_edge,
            Tb + (size_t)l * 8192,
            wrB + (size_t)l * 4096, aggc);
        const bf16* wbn = (l + 1 < DEPTH) ? (wb + (size_t)(l + 1) * 32768) : nullptr;
        layer_k<<<N_NODES / 64, 512, 0, stream>>>(
            h, aggc, wc + (size_t)l * 81920, post_b + l * HID, wbn, z12);
    }

    readout<<<N_GRAPHS, 128, 0, stream>>>(h, ro_W1, ro_b1, ro_W2, ro_b2, (float*)d_out);
}

// Round 12
// 380.488 us; speedup vs baseline: 1.8474x; 1.0236x over previous
//
#include <hip/hip_runtime.h>
#include <hip/hip_bf16.h>

#define N_NODES 32768
#define N_EDGES 196608
#define N_GRAPHS 256
#define DEG 6
#define HID 128
#define RVD 16
#define EMB 112
#define VOCAB 128
#define TGT 256
#define DEPTH 5

#define LOG7 1.9459101090932196f
#define ILOG7 0.5138983423697507f

typedef __hip_bfloat16 bf16;
using frag_ab = __attribute__((ext_vector_type(8))) short;   // 8 bf16
using frag_cd = __attribute__((ext_vector_type(4))) float;   // 4 f32

static __device__ __forceinline__ float b2f(bf16 x) { return __bfloat162float(x); }
static __device__ __forceinline__ bf16  f2b(float x) { return __float2bfloat16(x); }
static __device__ __forceinline__ short f2s(float x) {
    bf16 b = __float2bfloat16(x);
    return *reinterpret_cast<short*>(&b);
}
static __device__ __forceinline__ float us2f(unsigned short u) {
    unsigned int x = ((unsigned int)u) << 16;
    return __uint_as_float(x);
}
static __device__ __forceinline__ unsigned short f2us(float x) {
    bf16 b = __float2bfloat16(x);
    return *reinterpret_cast<unsigned short*>(&b);
}

// ---------------- unified prep: encode + packs + bond table, one dispatch ----------------
// block ranges: [0,16384) encode(2 nodes) | [+640) pack_wb | [+1600) pack_wc
//               | [+80) pack_wr | [+768) bond_code | [+320) bond_T(inline bondsum)
#define PB_ENC  16384
#define PB_WB   (PB_ENC + 640)
#define PB_WC   (PB_WB + 1600)
#define PB_WR   (PB_WC + 80)
#define PB_CODE (PB_WR + 768)
#define PB_T    (PB_CODE + 320)

__global__ __launch_bounds__(256) void prep_k(const int* __restrict__ af, const float* __restrict__ rx,
                                              const float* __restrict__ aemb, bf16* __restrict__ h,
                                              const float* __restrict__ preW, const float* __restrict__ preB,
                                              const float* __restrict__ postW,
                                              const int* __restrict__ bfeat, const float* __restrict__ bemb,
                                              bf16* __restrict__ wb, bf16* __restrict__ wc,
                                              bf16* __restrict__ wrB, unsigned char* __restrict__ codeA,
                                              bf16* __restrict__ Tb) {
    int blk = blockIdx.x, tid = threadIdx.x;
    if (blk < PB_ENC) {
        // encode 2 nodes per block
        int v = blk * 2 + (tid >> 7), c = tid & 127;
        float val;
        if (c < EMB) {
            val = 0.f;
            #pragma unroll
            for (int i = 0; i < 9; ++i) {
                int f = af[v * 9 + i];
                val += aemb[(i * VOCAB + f) * EMB + c];
            }
        } else {
            val = rx[v * RVD + (c - EMB)];
        }
        h[(size_t)v * HID + c] = f2b(val);
    } else if (blk < PB_WB) {
        int idx = (blk - PB_ENC) * 256 + tid;
        if (idx < DEPTH * 32768) {
            int j = idx & 7, L = (idx >> 3) & 63, nt = (idx >> 9) & 15, ks = (idx >> 13) & 3, l = idx >> 15;
            int k = ks * 32 + ((L >> 4) * 8) + j;
            int n = nt * 16 + (L & 15);
            const float* W = preW + (size_t)l * 384 * 128;
            float v = (n < 128) ? W[k * 128 + n] : W[(128 + k) * 128 + (n - 128)];
            wb[idx] = f2b(v);
        }
    } else if (blk < PB_WC) {
        int idx = (blk - PB_WB) * 256 + tid;
        if (idx < DEPTH * 81920) {
            int j = idx & 7, L = (idx >> 3) & 63, nt = (idx >> 9) & 7;
            int t = idx >> 12;
            int ks = t % 20, l = t / 20;
            int k = ks * 32 + ((L >> 4) * 8) + j;
            int n = nt * 16 + (L & 15);
            const float* W = postW + (size_t)l * 1664 * 128;
            float v;
            if (k < 128) {
                v = W[k * 128 + n];
            } else {
                int jj = k - 128;
                v = W[(128 + jj) * 128 + n] + LOG7 * W[(640 + jj) * 128 + n] + ILOG7 * W[(1152 + jj) * 128 + n];
            }
            wc[idx] = f2b(v);
        }
    } else if (blk < PB_WR) {
        int idx = (blk - PB_WC) * 256 + tid;
        if (idx < DEPTH * 4096) {
            int j = idx & 7, L = (idx >> 3) & 63, nt = (idx >> 9) & 7, l = idx >> 12;
            int k = ((L >> 4) * 8) + j;
            int n = nt * 16 + (L & 15);
            float v = (k < 16) ? preW[(size_t)l * 384 * 128 + (368 + k) * 128 + n] : 0.f;
            wrB[idx] = f2b(v);
        }
    } else if (blk < PB_CODE) {
        int e = (blk - PB_WR) * 256 + tid;
        if (e < N_EDGES)
            codeA[e] = (unsigned char)(bfeat[e * 3] | (bfeat[e * 3 + 1] << 2) | (bfeat[e * 3 + 2] << 4));
    } else {
        // bond_T with inline bond-sum (bemb reads are wave-uniform scalar loads)
        if (tid < 128) {
            int t = blk - PB_CODE;
            int l = t >> 6, cd = t & 63, c = tid;
            int f0 = cd & 3, f1 = (cd >> 2) & 3, f2 = cd >> 4;
            const float* W = preW + (size_t)l * 384 * 128 + 256 * 128;
            float acc = preB[l * 128 + c];
            #pragma unroll 4
            for (int k = 0; k < EMB; ++k) {
                float bsk = bemb[(0 * VOCAB + f0) * EMB + k]
                          + bemb[(1 * VOCAB + f1) * EMB + k]
                          + bemb[(2 * VOCAB + f2) * EMB + k];
                acc += bsk * W[k * 128 + c];
            }
            Tb[(size_t)(l * 64 + cd) * 128 + c] = f2b(acc);
        }
    }
}

// ---------------- layer-0 Z12 GEMM: z12 = h @ wb0 ----------------
__global__ __launch_bounds__(256) void gemm_z12(const bf16* __restrict__ A,
                                                const bf16* __restrict__ Bp,
                                                bf16* __restrict__ C) {
    int lane = threadIdx.x & 63;
    int wave = threadIdx.x >> 6;
    int m = lane & 15, quad = lane >> 4;
    int row0 = blockIdx.x * 64 + wave * 16;

    frag_cd acc[16];
    #pragma unroll
    for (int nt = 0; nt < 16; ++nt)
        #pragma unroll
        for (int i = 0; i < 4; ++i) acc[nt][i] = 0.f;

    const frag_ab* Bf = (const frag_ab*)Bp;
    const bf16* arow = A + (size_t)(row0 + m) * 128;
    #pragma unroll
    for (int ks = 0; ks < 4; ++ks) {
        frag_ab a = *(const frag_ab*)(arow + ks * 32 + quad * 8);
        #pragma unroll
        for (int nt = 0; nt < 16; ++nt) {
            frag_ab b = Bf[(ks * 16 + nt) * 64 + lane];
            acc[nt] = __builtin_amdgcn_mfma_f32_16x16x32_bf16(a, b, acc[nt], 0, 0, 0);
        }
    }
    #pragma unroll
    for (int nt = 0; nt < 16; ++nt) {
        int col = nt * 16 + m;
        #pragma unroll
        for (int r = 0; r < 4; ++r) {
            int row = row0 + quad * 4 + r;
            C[(size_t)row * 256 + col] = f2b(acc[nt][r]);
        }
    }
}

// ---------------- fused posttrans + residual + next-layer Z12 ----------------
// 64-row tile, 512 threads / 8 waves: wave = (rt 0..3, nh 0..1). grid = N/64 = 512.
__global__ __launch_bounds__(512) void layer_k(bf16* __restrict__ h,       // bf16 state, in-place
                                               const bf16* __restrict__ aggc,
                                               const bf16* __restrict__ Bp,
                                               const float* __restrict__ bias,
                                               const bf16* __restrict__ Bn,
                                               bf16* __restrict__ z12) {
    __shared__ __align__(16) bf16 newh[64 * 136];   // pad 136: b128-aligned rows
    int lane = threadIdx.x & 63;
    int wave = threadIdx.x >> 6;
    int rt = wave & 3;        // row-tile
    int nh = wave >> 2;       // col-half
    int m = lane & 15, quad = lane >> 4;
    int row0 = blockIdx.x * 64;
    int rowA = row0 + rt * 16 + m;

    frag_cd acc[4];
    #pragma unroll
    for (int nt = 0; nt < 4; ++nt)
        #pragma unroll
        for (int i = 0; i < 4; ++i) acc[nt][i] = 0.f;

    const frag_ab* Bf = (const frag_ab*)Bp;
    const bf16* arow = h + (size_t)rowA * 128;
    #pragma unroll
    for (int ks = 0; ks < 4; ++ks) {
        frag_ab a = *(const frag_ab*)(arow + ks * 32 + quad * 8);
        #pragma unroll
        for (int nt = 0; nt < 4; ++nt) {
            frag_ab b = Bf[(ks * 8 + nh * 4 + nt) * 64 + lane];
            acc[nt] = __builtin_amdgcn_mfma_f32_16x16x32_bf16(a, b, acc[nt], 0, 0, 0);
        }
    }
    const bf16* grow = aggc + (size_t)rowA * 512;
    #pragma unroll
    for (int ks = 0; ks < 16; ++ks) {
        frag_ab a = *(const frag_ab*)(grow + ks * 32 + quad * 8);
        #pragma unroll
        for (int nt = 0; nt < 4; ++nt) {
            frag_ab b = Bf[((4 + ks) * 8 + nh * 4 + nt) * 64 + lane];
            acc[nt] = __builtin_amdgcn_mfma_f32_16x16x32_bf16(a, b, acc[nt], 0, 0, 0);
        }
    }

    __syncthreads();   // all waves done reading h rows before any in-place write

    #pragma unroll
    for (int nt = 0; nt < 4; ++nt) {
        int col = nh * 64 + nt * 16 + m;
        float bs_ = bias[col];
        #pragma unroll
        for (int r = 0; r < 4; ++r) {
            int lr = rt * 16 + quad * 4 + r;
            int row = row0 + lr;
            float nv = acc[nt][r] + bs_ + b2f(h[(size_t)row * HID + col]);
            bf16 bv = f2b(nv);
            h[(size_t)row * HID + col] = bv;
            newh[lr * 136 + col] = bv;
        }
    }

    if (Bn) {
        __syncthreads();
        const frag_ab* Bf2 = (const frag_ab*)Bn;
        frag_cd a2[8];
        #pragma unroll
        for (int nt = 0; nt < 8; ++nt)
            #pragma unroll
            for (int i = 0; i < 4; ++i) a2[nt][i] = 0.f;
        #pragma unroll
        for (int ks = 0; ks < 4; ++ks) {
            frag_ab a = *(const frag_ab*)&newh[(rt * 16 + m) * 136 + ks * 32 + quad * 8];
            #pragma unroll
            for (int nt = 0; nt < 8; ++nt) {
                frag_ab b = Bf2[(ks * 16 + nh * 8 + nt) * 64 + lane];
                a2[nt] = __builtin_amdgcn_mfma_f32_16x16x32_bf16(a, b, a2[nt], 0, 0, 0);
            }
        }
        #pragma unroll
        for (int nt = 0; nt < 8; ++nt) {
            int col = nh * 128 + nt * 16 + m;
            #pragma unroll
            for (int r = 0; r < 4; ++r) {
                int row = row0 + rt * 16 + quad * 4 + r;
                z12[(size_t)row * 256 + col] = f2b(a2[nt][r]);
            }
        }
    }
}

// ---------------- fused edge-transform + aggregation ----------------
// Phase 0: rdot[48,128] = rnd[48,16] @ Wr via MFMA (3 waves x 8 n-tiles, K=16 zero-padded)
// Phase A: 2 channels/thread, all gathers ushort2 (4B): 64 threads/node-row.
__global__ __launch_bounds__(256) void fused_agg(const bf16* __restrict__ Z12,
                                                 const int* __restrict__ src,
                                                 const unsigned char* __restrict__ code,
                                                 const float* __restrict__ rand_edge,
                                                 const bf16* __restrict__ Tb,
                                                 const bf16* __restrict__ WrB,
                                                 bf16* __restrict__ aggc) {
    __shared__ __align__(16) float rdot[48 * 130];   // 24.4 KB; stride 130 spreads quad rows across banks
    int tid = threadIdx.x;
    int lane = tid & 63, wave = tid >> 6;
    int bv = blockIdx.x * 8;

    // ---- phase 0 ----
    if (wave < 3) {
        int m = lane & 15, quad = lane >> 4;
        frag_ab a;
        if (quad < 2) {
            const float4* rp = (const float4*)(rand_edge
                + ((size_t)blockIdx.x * 48 + wave * 16 + m) * 16 + quad * 8);
            float4 A = rp[0], B = rp[1];
            a[0] = f2s(A.x); a[1] = f2s(A.y); a[2] = f2s(A.z); a[3] = f2s(A.w);
            a[4] = f2s(B.x); a[5] = f2s(B.y); a[6] = f2s(B.z); a[7] = f2s(B.w);
        } else {
            #pragma unroll
            for (int j = 0; j < 8; ++j) a[j] = 0;
        }
        const frag_ab* Bf = (const frag_ab*)WrB;
        #pragma unroll
        for (int nt = 0; nt < 8; ++nt) {
            frag_cd acc;
            #pragma unroll
            for (int i = 0; i < 4; ++i) acc[i] = 0.f;
            acc = __builtin_amdgcn_mfma_f32_16x16x32_bf16(a, Bf[nt * 64 + lane], acc, 0, 0, 0);
            #pragma unroll
            for (int r = 0; r < 4; ++r)
                rdot[(wave * 16 + quad * 4 + r) * 130 + nt * 16 + m] = acc[r];
        }
    }
    __syncthreads();

    // ---- phase A: 2 channels per thread, 64 threads per node ----
    const unsigned short* Zu = (const unsigned short*)Z12;
    const unsigned short* Tu = (const unsigned short*)Tb;
    unsigned short* Au = (unsigned short*)aggc;
    int c = lane * 2;          // even channel pair
    int g = wave;              // node group 0..3, 2 nodes each

    #pragma unroll
    for (int i = 0; i < 2; ++i) {
        int nb = g * 2 + i;
        int v = bv + nb;
        ushort2 z2u = *(const ushort2*)(Zu + (size_t)v * 256 + 128 + c);
        float z2a = us2f(z2u.x), z2b = us2f(z2u.y);
        const int2* sp = (const int2*)(src + v * 6);
        int2 s01 = sp[0], s23 = sp[1], s45 = sp[2];
        const unsigned short* cp = (const unsigned short*)(code + v * 6);
        unsigned short c01 = cp[0], c23 = cp[1], c45 = cp[2];
        int svs[6] = { s01.x, s01.y, s23.x, s23.y, s45.x, s45.y };
        int cds[6] = { c01 & 255, c01 >> 8, c23 & 255, c23 >> 8, c45 & 255, c45 >> 8 };
        ushort2 z1u[6], tvu[6];
        #pragma unroll
        for (int j = 0; j < 6; ++j) z1u[j] = *(const ushort2*)(Zu + (size_t)svs[j] * 256 + c);
        #pragma unroll
        for (int j = 0; j < 6; ++j) tvu[j] = *(const ushort2*)(Tu + cds[j] * 128 + c);
        float sa = 0.f, ssa = 0.f, mxa = -1e30f, mna = 1e30f;
        float sb = 0.f, ssb = 0.f, mxb = -1e30f, mnb = 1e30f;
        #pragma unroll
        for (int j = 0; j < 6; ++j) {
            const float2 rd = *(const float2*)(rdot + (nb * 6 + j) * 130 + c);
            float va = us2f(z1u[j].x) + z2a + us2f(tvu[j].x) + rd.x;
            float vb = us2f(z1u[j].y) + z2b + us2f(tvu[j].y) + rd.y;
            va = fmaxf(va, 0.f);
            vb = fmaxf(vb, 0.f);
            sa += va; ssa += va * va; mxa = fmaxf(mxa, va); mna = fminf(mna, va);
            sb += vb; ssb += vb * vb; mxb = fmaxf(mxb, vb); mnb = fminf(mnb, vb);
        }
        float meana = sa * (1.f / 6.f), meanb = sb * (1.f / 6.f);
        float msqa = ssa * (1.f / 6.f), msqb = ssb * (1.f / 6.f);
        float sda = sqrtf(fmaxf(msqa - meana * meana, 0.f) + 1e-5f);
        float sdb = sqrtf(fmaxf(msqb - meanb * meanb, 0.f) + 1e-5f);
        size_t base = (size_t)v * 512 + c;
        *(ushort2*)(Au + base)       = make_ushort2(f2us(meana), f2us(meanb));
        *(ushort2*)(Au + base + 128) = make_ushort2(f2us(mxa),  f2us(mxb));
        *(ushort2*)(Au + base + 256) = make_ushort2(f2us(mna),  f2us(mnb));
        *(ushort2*)(Au + base + 384) = make_ushort2(f2us(sda),  f2us(sdb));
    }
}

// ---------------- readout ----------------
__global__ __launch_bounds__(128) void readout(const bf16* __restrict__ h, const float* __restrict__ W1,
                                               const float* __restrict__ b1, const float* __restrict__ W2,
                                               const float* __restrict__ b2, float* __restrict__ out) {
    __shared__ float r[384];
    __shared__ float y1[128];
    int g = blockIdx.x, c = threadIdx.x;
    float s = 0.f, mx = -1e30f;
    for (int v = 0; v < 128; ++v) {
        float hv = b2f(h[((size_t)g * 128 + v) * HID + c]);
        s += hv; mx = fmaxf(mx, hv);
    }
    r[c] = s * (1.f / 128.f);
    r[128 + c] = s;
    r[256 + c] = mx;
    __syncthreads();
    float a1 = b1[c];
    for (int k = 0; k < 384; ++k) a1 += r[k] * W1[k * 128 + c];
    y1[c] = fmaxf(a1, 0.f);
    __syncthreads();
    #pragma unroll
    for (int o = 0; o < 2; ++o) {
        int t = c + o * 128;
        float a2 = b2[t];
        for (int k = 0; k < 128; ++k) a2 += y1[k] * W2[k * 256 + t];
        out[(size_t)g * 256 + t] = a2;
    }
}

// ---------------- launch ----------------
extern "C" void kernel_launch(void* const* d_in, const int* in_sizes, int n_in,
                              void* d_out, int out_size, void* d_ws, size_t ws_size,
                              hipStream_t stream) {
    const int*   atom_feats = (const int*)d_in[0];
    const int*   bond_feats = (const int*)d_in[1];
    const int*   src        = (const int*)d_in[2];
    const float* rand_x     = (const float*)d_in[6];
    const float* rand_edge  = (const float*)d_in[7];
    const float* atom_emb   = (const float*)d_in[8];
    const float* bond_emb   = (const float*)d_in[9];
    const float* pre_W      = (const float*)d_in[10];
    const float* pre_b      = (const float*)d_in[11];
    const float* post_W     = (const float*)d_in[12];
    const float* post_b     = (const float*)d_in[13];
    const float* ro_W1      = (const float*)d_in[14];
    const float* ro_b1      = (const float*)d_in[15];
    const float* ro_W2      = (const float*)d_in[16];
    const float* ro_b2      = (const float*)d_in[17];

    char* p = (char*)d_ws;
    auto alloc = [&](size_t bytes) {
        char* r = p;
        p += (bytes + 255) & ~(size_t)255;
        return r;
    };
    bf16*  h    = (bf16*) alloc((size_t)N_NODES * HID * 2);      // 8 MB (bf16 state)
    bf16*  z12  = (bf16*) alloc((size_t)N_NODES * 256 * 2);      // 16 MB
    bf16*  aggc = (bf16*) alloc((size_t)N_NODES * 512 * 2);      // 32 MB
    bf16*  wb   = (bf16*) alloc((size_t)DEPTH * 32768 * 2);
    bf16*  wc   = (bf16*) alloc((size_t)DEPTH * 81920 * 2);
    bf16*  wrB  = (bf16*) alloc((size_t)DEPTH * 4096 * 2);       // 40 KB
    bf16*  Tb   = (bf16*) alloc((size_t)DEPTH * 64 * 128 * 2);   // 80 KB
    unsigned char* code = (unsigned char*)alloc(N_EDGES);        // 192 KB

    // unified prep (encode + all packs + bond table)
    prep_k<<<PB_T, 256, 0, stream>>>(atom_feats, rand_x, atom_emb, h,
                                     pre_W, pre_b, post_W,
                                     bond_feats, bond_emb,
                                     wb, wc, wrB, code, Tb);

    // layer-0 Z12
    gemm_z12<<<N_NODES / 64, 256, 0, stream>>>(h, wb, z12);

    for (int l = 0; l < DEPTH; ++l) {
        fused_agg<<<N_NODES / 8, 256, 0, stream>>>(
            z12, src, code, rand_edge,
            Tb + (size_t)l * 8192,
            wrB + (size_t)l * 4096, aggc);
        const bf16* wbn = (l + 1 < DEPTH) ? (wb + (size_t)(l + 1) * 32768) : nullptr;
        layer_k<<<N_NODES / 64, 512, 0, stream>>>(
            h, aggc, wc + (size_t)l * 81920, post_b + l * HID, wbn, z12);
    }

    readout<<<N_GRAPHS, 128, 0, stream>>>(h, ro_W1, ro_b1, ro_W2, ro_b2, (float*)d_out);
}

// Round 13
// 376.617 us; speedup vs baseline: 1.8663x; 1.0103x over previous
//
#include <hip/hip_runtime.h>
#include <hip/hip_bf16.h>

#define N_NODES 32768
#define N_EDGES 196608
#define N_GRAPHS 256
#define DEG 6
#define HID 128
#define RVD 16
#define EMB 112
#define VOCAB 128
#define TGT 256
#define DEPTH 5

#define LOG7 1.9459101090932196f
#define ILOG7 0.5138983423697507f

typedef __hip_bfloat16 bf16;
using frag_ab = __attribute__((ext_vector_type(8))) short;   // 8 bf16
using frag_cd = __attribute__((ext_vector_type(4))) float;   // 4 f32

static __device__ __forceinline__ float b2f(bf16 x) { return __bfloat162float(x); }
static __device__ __forceinline__ bf16  f2b(float x) { return __float2bfloat16(x); }
static __device__ __forceinline__ short f2s(float x) {
    bf16 b = __float2bfloat16(x);
    return *reinterpret_cast<short*>(&b);
}
static __device__ __forceinline__ float us2f(unsigned short u) {
    unsigned int x = ((unsigned int)u) << 16;
    return __uint_as_float(x);
}
static __device__ __forceinline__ unsigned short f2us(float x) {
    bf16 b = __float2bfloat16(x);
    return *reinterpret_cast<unsigned short*>(&b);
}

// ---------------- unified prep: encode + packs + bond table, one dispatch ----------------
#define PB_ENC  16384
#define PB_WB   (PB_ENC + 640)
#define PB_WC   (PB_WB + 1600)
#define PB_WR   (PB_WC + 80)
#define PB_CODE (PB_WR + 768)
#define PB_T    (PB_CODE + 320)

__global__ __launch_bounds__(256) void prep_k(const int* __restrict__ af, const float* __restrict__ rx,
                                              const float* __restrict__ aemb, bf16* __restrict__ h,
                                              const float* __restrict__ preW, const float* __restrict__ preB,
                                              const float* __restrict__ postW,
                                              const int* __restrict__ bfeat, const float* __restrict__ bemb,
                                              bf16* __restrict__ wb, bf16* __restrict__ wc,
                                              bf16* __restrict__ wrB, unsigned char* __restrict__ codeA,
                                              bf16* __restrict__ Tb) {
    int blk = blockIdx.x, tid = threadIdx.x;
    if (blk < PB_ENC) {
        int v = blk * 2 + (tid >> 7), c = tid & 127;
        float val;
        if (c < EMB) {
            val = 0.f;
            #pragma unroll
            for (int i = 0; i < 9; ++i) {
                int f = af[v * 9 + i];
                val += aemb[(i * VOCAB + f) * EMB + c];
            }
        } else {
            val = rx[v * RVD + (c - EMB)];
        }
        h[(size_t)v * HID + c] = f2b(val);
    } else if (blk < PB_WB) {
        int idx = (blk - PB_ENC) * 256 + tid;
        if (idx < DEPTH * 32768) {
            int j = idx & 7, L = (idx >> 3) & 63, nt = (idx >> 9) & 15, ks = (idx >> 13) & 3, l = idx >> 15;
            int k = ks * 32 + ((L >> 4) * 8) + j;
            int n = nt * 16 + (L & 15);
            const float* W = preW + (size_t)l * 384 * 128;
            float v = (n < 128) ? W[k * 128 + n] : W[(128 + k) * 128 + (n - 128)];
            wb[idx] = f2b(v);
        }
    } else if (blk < PB_WC) {
        int idx = (blk - PB_WB) * 256 + tid;
        if (idx < DEPTH * 81920) {
            int j = idx & 7, L = (idx >> 3) & 63, nt = (idx >> 9) & 7;
            int t = idx >> 12;
            int ks = t % 20, l = t / 20;
            int k = ks * 32 + ((L >> 4) * 8) + j;
            int n = nt * 16 + (L & 15);
            const float* W = postW + (size_t)l * 1664 * 128;
            float v;
            if (k < 128) {
                v = W[k * 128 + n];
            } else {
                int jj = k - 128;
                v = W[(128 + jj) * 128 + n] + LOG7 * W[(640 + jj) * 128 + n] + ILOG7 * W[(1152 + jj) * 128 + n];
            }
            wc[idx] = f2b(v);
        }
    } else if (blk < PB_WR) {
        int idx = (blk - PB_WC) * 256 + tid;
        if (idx < DEPTH * 4096) {
            int j = idx & 7, L = (idx >> 3) & 63, nt = (idx >> 9) & 7, l = idx >> 12;
            int k = ((L >> 4) * 8) + j;
            int n = nt * 16 + (L & 15);
            float v = (k < 16) ? preW[(size_t)l * 384 * 128 + (368 + k) * 128 + n] : 0.f;
            wrB[idx] = f2b(v);
        }
    } else if (blk < PB_CODE) {
        int e = (blk - PB_WR) * 256 + tid;
        if (e < N_EDGES)
            codeA[e] = (unsigned char)(bfeat[e * 3] | (bfeat[e * 3 + 1] << 2) | (bfeat[e * 3 + 2] << 4));
    } else {
        if (tid < 128) {
            int t = blk - PB_CODE;
            int l = t >> 6, cd = t & 63, c = tid;
            int f0 = cd & 3, f1 = (cd >> 2) & 3, f2 = cd >> 4;
            const float* W = preW + (size_t)l * 384 * 128 + 256 * 128;
            float acc = preB[l * 128 + c];
            #pragma unroll 4
            for (int k = 0; k < EMB; ++k) {
                float bsk = bemb[(0 * VOCAB + f0) * EMB + k]
                          + bemb[(1 * VOCAB + f1) * EMB + k]
                          + bemb[(2 * VOCAB + f2) * EMB + k];
                acc += bsk * W[k * 128 + c];
            }
            Tb[(size_t)(l * 64 + cd) * 128 + c] = f2b(acc);
        }
    }
}

// ---------------- layer-0 Z12 GEMM: z12 = h @ wb0 ----------------
__global__ __launch_bounds__(256) void gemm_z12(const bf16* __restrict__ A,
                                                const bf16* __restrict__ Bp,
                                                bf16* __restrict__ C) {
    int lane = threadIdx.x & 63;
    int wave = threadIdx.x >> 6;
    int m = lane & 15, quad = lane >> 4;
    int row0 = blockIdx.x * 64 + wave * 16;

    frag_cd acc[16];
    #pragma unroll
    for (int nt = 0; nt < 16; ++nt)
        #pragma unroll
        for (int i = 0; i < 4; ++i) acc[nt][i] = 0.f;

    const frag_ab* Bf = (const frag_ab*)Bp;
    const bf16* arow = A + (size_t)(row0 + m) * 128;
    #pragma unroll
    for (int ks = 0; ks < 4; ++ks) {
        frag_ab a = *(const frag_ab*)(arow + ks * 32 + quad * 8);
        #pragma unroll
        for (int nt = 0; nt < 16; ++nt) {
            frag_ab b = Bf[(ks * 16 + nt) * 64 + lane];
            acc[nt] = __builtin_amdgcn_mfma_f32_16x16x32_bf16(a, b, acc[nt], 0, 0, 0);
        }
    }
    #pragma unroll
    for (int nt = 0; nt < 16; ++nt) {
        int col = nt * 16 + m;
        #pragma unroll
        for (int r = 0; r < 4; ++r) {
            int row = row0 + quad * 4 + r;
            C[(size_t)row * 256 + col] = f2b(acc[nt][r]);
        }
    }
}

// ---------------- fused posttrans + residual + next-layer Z12 ----------------
// 64-row tile, 512 threads / 8 waves: wave = (rt 0..3, nh 0..1). grid = N/64 = 512.
__global__ __launch_bounds__(512) void layer_k(bf16* __restrict__ h,       // bf16 state, in-place
                                               const bf16* __restrict__ aggc,
                                               const bf16* __restrict__ Bp,
                                               const float* __restrict__ bias,
                                               const bf16* __restrict__ Bn,
                                               bf16* __restrict__ z12) {
    __shared__ __align__(16) bf16 newh[64 * 136];   // pad 136: b128-aligned rows
    int lane = threadIdx.x & 63;
    int wave = threadIdx.x >> 6;
    int rt = wave & 3;        // row-tile
    int nh = wave >> 2;       // col-half
    int m = lane & 15, quad = lane >> 4;
    int row0 = blockIdx.x * 64;
    int rowA = row0 + rt * 16 + m;

    frag_cd acc[4];
    #pragma unroll
    for (int nt = 0; nt < 4; ++nt)
        #pragma unroll
        for (int i = 0; i < 4; ++i) acc[nt][i] = 0.f;

    const frag_ab* Bf = (const frag_ab*)Bp;
    const bf16* arow = h + (size_t)rowA * 128;
    #pragma unroll
    for (int ks = 0; ks < 4; ++ks) {
        frag_ab a = *(const frag_ab*)(arow + ks * 32 + quad * 8);
        #pragma unroll
        for (int nt = 0; nt < 4; ++nt) {
            frag_ab b = Bf[(ks * 8 + nh * 4 + nt) * 64 + lane];
            acc[nt] = __builtin_amdgcn_mfma_f32_16x16x32_bf16(a, b, acc[nt], 0, 0, 0);
        }
    }
    const bf16* grow = aggc + (size_t)rowA * 512;
    #pragma unroll
    for (int ks = 0; ks < 16; ++ks) {
        frag_ab a = *(const frag_ab*)(grow + ks * 32 + quad * 8);
        #pragma unroll
        for (int nt = 0; nt < 4; ++nt) {
            frag_ab b = Bf[((4 + ks) * 8 + nh * 4 + nt) * 64 + lane];
            acc[nt] = __builtin_amdgcn_mfma_f32_16x16x32_bf16(a, b, acc[nt], 0, 0, 0);
        }
    }

    __syncthreads();   // all waves done reading h rows before any in-place write

    #pragma unroll
    for (int nt = 0; nt < 4; ++nt) {
        int col = nh * 64 + nt * 16 + m;
        float bs_ = bias[col];
        #pragma unroll
        for (int r = 0; r < 4; ++r) {
            int lr = rt * 16 + quad * 4 + r;
            int row = row0 + lr;
            float nv = acc[nt][r] + bs_ + b2f(h[(size_t)row * HID + col]);
            bf16 bv = f2b(nv);
            h[(size_t)row * HID + col] = bv;
            newh[lr * 136 + col] = bv;
        }
    }

    if (Bn) {
        __syncthreads();
        const frag_ab* Bf2 = (const frag_ab*)Bn;
        frag_cd a2[8];
        #pragma unroll
        for (int nt = 0; nt < 8; ++nt)
            #pragma unroll
            for (int i = 0; i < 4; ++i) a2[nt][i] = 0.f;
        #pragma unroll
        for (int ks = 0; ks < 4; ++ks) {
            frag_ab a = *(const frag_ab*)&newh[(rt * 16 + m) * 136 + ks * 32 + quad * 8];
            #pragma unroll
            for (int nt = 0; nt < 8; ++nt) {
                frag_ab b = Bf2[(ks * 16 + nh * 8 + nt) * 64 + lane];
                a2[nt] = __builtin_amdgcn_mfma_f32_16x16x32_bf16(a, b, a2[nt], 0, 0, 0);
            }
        }
        #pragma unroll
        for (int nt = 0; nt < 8; ++nt) {
            int col = nh * 128 + nt * 16 + m;
            #pragma unroll
            for (int r = 0; r < 4; ++r) {
                int row = row0 + rt * 16 + quad * 4 + r;
                z12[(size_t)row * 256 + col] = f2b(a2[nt][r]);
            }
        }
    }
}

// ---------------- fused edge-transform + aggregation ----------------
// XCD-aware block swizzle: block b = 8t + x runs on XCD x (round-robin assumption);
// it processes sub-block (t&7) of 64-node window w = x + 8*(t>>3), so all 8 producers
// of window w share the XCD of consumer layer_k block w (also dispatched to XCD w%8).
// Pure work->block permutation: numerics identical; worst case (mapping changed) = old speed.
__global__ __launch_bounds__(256) void fused_agg(const bf16* __restrict__ Z12,
                                                 const int* __restrict__ src,
                                                 const unsigned char* __restrict__ code,
                                                 const float* __restrict__ rand_edge,
                                                 const bf16* __restrict__ Tb,
                                                 const bf16* __restrict__ WrB,
                                                 bf16* __restrict__ aggc) {
    __shared__ __align__(16) float rdot[48 * 130];   // 24.4 KB; stride 130 spreads quad rows across banks
    int tid = threadIdx.x;
    int lane = tid & 63, wave = tid >> 6;
    int xb = blockIdx.x & 7, tb = blockIdx.x >> 3;
    int w = xb + 8 * (tb >> 3);
    int bv = w * 64 + (tb & 7) * 8;

    // ---- phase 0: rdot[48,128] = rnd[48,16] @ Wr via MFMA ----
    if (wave < 3) {
        int m = lane & 15, quad = lane >> 4;
        frag_ab a;
        if (quad < 2) {
            const float4* rp = (const float4*)(rand_edge
                + (size_t)(bv * 6 + wave * 16 + m) * 16 + quad * 8);
            float4 A = rp[0], B = rp[1];
            a[0] = f2s(A.x); a[1] = f2s(A.y); a[2] = f2s(A.z); a[3] = f2s(A.w);
            a[4] = f2s(B.x); a[5] = f2s(B.y); a[6] = f2s(B.z); a[7] = f2s(B.w);
        } else {
            #pragma unroll
            for (int j = 0; j < 8; ++j) a[j] = 0;
        }
        const frag_ab* Bf = (const frag_ab*)WrB;
        #pragma unroll
        for (int nt = 0; nt < 8; ++nt) {
            frag_cd acc;
            #pragma unroll
            for (int i = 0; i < 4; ++i) acc[i] = 0.f;
            acc = __builtin_amdgcn_mfma_f32_16x16x32_bf16(a, Bf[nt * 64 + lane], acc, 0, 0, 0);
            #pragma unroll
            for (int r = 0; r < 4; ++r)
                rdot[(wave * 16 + quad * 4 + r) * 130 + nt * 16 + m] = acc[r];
        }
    }
    __syncthreads();

    // ---- phase A: 2 channels per thread, 64 threads per node ----
    const unsigned short* Zu = (const unsigned short*)Z12;
    const unsigned short* Tu = (const unsigned short*)Tb;
    unsigned short* Au = (unsigned short*)aggc;
    int c = lane * 2;          // even channel pair
    int g = wave;              // node group 0..3, 2 nodes each

    #pragma unroll
    for (int i = 0; i < 2; ++i) {
        int nb = g * 2 + i;
        int v = bv + nb;
        ushort2 z2u = *(const ushort2*)(Zu + (size_t)v * 256 + 128 + c);
        float z2a = us2f(z2u.x), z2b = us2f(z2u.y);
        const int2* sp = (const int2*)(src + v * 6);
        int2 s01 = sp[0], s23 = sp[1], s45 = sp[2];
        const unsigned short* cp = (const unsigned short*)(code + v * 6);
        unsigned short c01 = cp[0], c23 = cp[1], c45 = cp[2];
        int svs[6] = { s01.x, s01.y, s23.x, s23.y, s45.x, s45.y };
        int cds[6] = { c01 & 255, c01 >> 8, c23 & 255, c23 >> 8, c45 & 255, c45 >> 8 };
        ushort2 z1u[6], tvu[6];
        #pragma unroll
        for (int j = 0; j < 6; ++j) z1u[j] = *(const ushort2*)(Zu + (size_t)svs[j] * 256 + c);
        #pragma unroll
        for (int j = 0; j < 6; ++j) tvu[j] = *(const ushort2*)(Tu + cds[j] * 128 + c);
        float sa = 0.f, ssa = 0.f, mxa = -1e30f, mna = 1e30f;
        float sb = 0.f, ssb = 0.f, mxb = -1e30f, mnb = 1e30f;
        #pragma unroll
        for (int j = 0; j < 6; ++j) {
            const float2 rd = *(const float2*)(rdot + ((nb * 6 + j) * 130) + c);
            float va = us2f(z1u[j].x) + z2a + us2f(tvu[j].x) + rd.x;
            float vb = us2f(z1u[j].y) + z2b + us2f(tvu[j].y) + rd.y;
            va = fmaxf(va, 0.f);
            vb = fmaxf(vb, 0.f);
            sa += va; ssa += va * va; mxa = fmaxf(mxa, va); mna = fminf(mna, va);
            sb += vb; ssb += vb * vb; mxb = fmaxf(mxb, vb); mnb = fminf(mnb, vb);
        }
        float meana = sa * (1.f / 6.f), meanb = sb * (1.f / 6.f);
        float msqa = ssa * (1.f / 6.f), msqb = ssb * (1.f / 6.f);
        float sda = sqrtf(fmaxf(msqa - meana * meana, 0.f) + 1e-5f);
        float sdb = sqrtf(fmaxf(msqb - meanb * meanb, 0.f) + 1e-5f);
        size_t base = (size_t)v * 512 + c;
        *(ushort2*)(Au + base)       = make_ushort2(f2us(meana), f2us(meanb));
        *(ushort2*)(Au + base + 128) = make_ushort2(f2us(mxa),  f2us(mxb));
        *(ushort2*)(Au + base + 256) = make_ushort2(f2us(mna),  f2us(mnb));
        *(ushort2*)(Au + base + 384) = make_ushort2(f2us(sda),  f2us(sdb));
    }
}

// ---------------- readout ----------------
__global__ __launch_bounds__(128) void readout(const bf16* __restrict__ h, const float* __restrict__ W1,
                                               const float* __restrict__ b1, const float* __restrict__ W2,
                                               const float* __restrict__ b2, float* __restrict__ out) {
    __shared__ float r[384];
    __shared__ float y1[128];
    int g = blockIdx.x, c = threadIdx.x;
    float s = 0.f, mx = -1e30f;
    for (int v = 0; v < 128; ++v) {
        float hv = b2f(h[((size_t)g * 128 + v) * HID + c]);
        s += hv; mx = fmaxf(mx, hv);
    }
    r[c] = s * (1.f / 128.f);
    r[128 + c] = s;
    r[256 + c] = mx;
    __syncthreads();
    float a1 = b1[c];
    for (int k = 0; k < 384; ++k) a1 += r[k] * W1[k * 128 + c];
    y1[c] = fmaxf(a1, 0.f);
    __syncthreads();
    #pragma unroll
    for (int o = 0; o < 2; ++o) {
        int t = c + o * 128;
        float a2 = b2[t];
        for (int k = 0; k < 128; ++k) a2 += y1[k] * W2[k * 256 + t];
        out[(size_t)g * 256 + t] = a2;
    }
}

// ---------------- launch ----------------
extern "C" void kernel_launch(void* const* d_in, const int* in_sizes, int n_in,
                              void* d_out, int out_size, void* d_ws, size_t ws_size,
                              hipStream_t stream) {
    const int*   atom_feats = (const int*)d_in[0];
    const int*   bond_feats = (const int*)d_in[1];
    const int*   src        = (const int*)d_in[2];
    const float* rand_x     = (const float*)d_in[6];
    const float* rand_edge  = (const float*)d_in[7];
    const float* atom_emb   = (const float*)d_in[8];
    const float* bond_emb   = (const float*)d_in[9];
    const float* pre_W      = (const float*)d_in[10];
    const float* pre_b      = (const float*)d_in[11];
    const float* post_W     = (const float*)d_in[12];
    const float* post_b     = (const float*)d_in[13];
    const float* ro_W1      = (const float*)d_in[14];
    const float* ro_b1      = (const float*)d_in[15];
    const float* ro_W2      = (const float*)d_in[16];
    const float* ro_b2      = (const float*)d_in[17];

    char* p = (char*)d_ws;
    auto alloc = [&](size_t bytes) {
        char* r = p;
        p += (bytes + 255) & ~(size_t)255;
        return r;
    };
    bf16*  h    = (bf16*) alloc((size_t)N_NODES * HID * 2);      // 8 MB (bf16 state)
    bf16*  z12  = (bf16*) alloc((size_t)N_NODES * 256 * 2);      // 16 MB
    bf16*  aggc = (bf16*) alloc((size_t)N_NODES * 512 * 2);      // 32 MB
    bf16*  wb   = (bf16*) alloc((size_t)DEPTH * 32768 * 2);
    bf16*  wc   = (bf16*) alloc((size_t)DEPTH * 81920 * 2);
    bf16*  wrB  = (bf16*) alloc((size_t)DEPTH * 4096 * 2);       // 40 KB
    bf16*  Tb   = (bf16*) alloc((size_t)DEPTH * 64 * 128 * 2);   // 80 KB
    unsigned char* code = (unsigned char*)alloc(N_EDGES);        // 192 KB

    // unified prep (encode + all packs + bond table)
    prep_k<<<PB_T, 256, 0, stream>>>(atom_feats, rand_x, atom_emb, h,
                                     pre_W, pre_b, post_W,
                                     bond_feats, bond_emb,
                                     wb, wc, wrB, code, Tb);

    // layer-0 Z12
    gemm_z12<<<N_NODES / 64, 256, 0, stream>>>(h, wb, z12);

    for (int l = 0; l < DEPTH; ++l) {
        fused_agg<<<N_NODES / 8, 256, 0, stream>>>(
            z12, src, code, rand_edge,
            Tb + (size_t)l * 8192,
            wrB + (size_t)l * 4096, aggc);
        const bf16* wbn = (l + 1 < DEPTH) ? (wb + (size_t)(l + 1) * 32768) : nullptr;
        layer_k<<<N_NODES / 64, 512, 0, stream>>>(
            h, aggc, wc + (size_t)l * 81920, post_b + l * HID, wbn, z12);
    }

    readout<<<N_GRAPHS, 128, 0, stream>>>(h, ro_W1, ro_b1, ro_W2, ro_b2, (float*)d_out);
}